// Round 2
// baseline (3517.427 us; speedup 1.0000x reference)
//
#include <hip/hip_runtime.h>

#define B_ 2
#define C_ 256
#define H_ 192
#define W_ 256
#define HW_ 49152
#define T_ 98304

// ============================ LN stats ============================
__global__ __launch_bounds__(256) void ln1_stats_kernel(
    const float* __restrict__ x, float* __restrict__ mean, float* __restrict__ rstd)
{
    int t = blockIdx.x * 256 + threadIdx.x;
    int b = t / HW_;
    int hw = t - b * HW_;
    const float* p = x + (size_t)b * C_ * HW_ + hw;
    float s = 0.f, q = 0.f;
    for (int c = 0; c < C_; ++c) {
        float v = p[(size_t)c * HW_];
        s += v; q += v * v;
    }
    float m = s * (1.f / C_);
    float var = q * (1.f / C_) - m * m;
    mean[t] = m;
    rstd[t] = rsqrtf(var + 1e-5f);
}

__global__ __launch_bounds__(256) void ln2_stats_kernel(
    const float* __restrict__ xr, float* __restrict__ mean, float* __restrict__ rstd)
{
    int wv = threadIdx.x >> 6, lane = threadIdx.x & 63;
    int t = blockIdx.x * 4 + wv;
    const float4 v = *(const float4*)(xr + (size_t)t * C_ + lane * 4);
    float s = v.x + v.y + v.z + v.w;
    float q = v.x * v.x + v.y * v.y + v.z * v.z + v.w * v.w;
    #pragma unroll
    for (int o = 32; o > 0; o >>= 1) {
        s += __shfl_xor(s, o);
        q += __shfl_xor(q, o);
    }
    if (lane == 0) {
        float m = s * (1.f / C_);
        float var = q * (1.f / C_) - m * m;
        mean[t] = m;
        rstd[t] = rsqrtf(var + 1e-5f);
    }
}

// ============================ GEMM ============================
// C[M,N] = A[M,K] @ W[N,K]^T (+ epilogue). M tiles along blockIdx.x, N along y.
// A_PLANAR_LN: A from planar x [B,C,H,W] with LN applied (conv_in)
// A_ROW:       A row-major [M,K] stride lda
// A_ROW_LN:    A row-major with per-row LN (fc1); mean/rstd indexed by local row
// A_CAT:       A = [A0 | A1] each [M,128] row-major stride lda (fuse)
// A_PLANAR_V:  A row r = (b,w,h) gather from ci[:,128:]; lda = global row offset
enum { A_PLANAR_LN = 0, A_ROW = 1, A_ROW_LN = 2, A_CAT = 3, A_PLANAR_V = 4 };
enum { E_BIAS = 0, E_GELU = 1, E_FFN2_FIRST = 2 };

constexpr int BM = 128, BN = 128, BK = 16;

template<int AMODE, int EMODE>
__global__ __launch_bounds__(256)
void gemm_kernel(const float* __restrict__ A0, const float* __restrict__ A1,
                 const float* __restrict__ Wt, const float* __restrict__ bias,
                 const float* __restrict__ mean, const float* __restrict__ rstd,
                 const float* __restrict__ lng, const float* __restrict__ lnb,
                 const float* __restrict__ resid, float* __restrict__ out,
                 int K, int lda, int ldw, int ldo)
{
    __shared__ float As[BK][BM + 4];
    __shared__ float Bs[BK][BN + 4];
    const int tid = threadIdx.x;
    const int t0 = blockIdx.x * BM;
    const int n0 = blockIdx.y * BN;
    const int tx = tid & 15, ty = tid >> 4;

    float acc[8][8];
    #pragma unroll
    for (int i = 0; i < 8; ++i)
        #pragma unroll
        for (int j = 0; j < 8; ++j) acc[i][j] = 0.f;

    for (int k0 = 0; k0 < K; k0 += BK) {
        // ---- A tile ----
        if (AMODE == A_PLANAR_LN) {
            const int lc = tid >> 4;            // channel within tile 0..15
            const int lt = (tid & 15) * 8;      // token offset 0..120
            const int t = t0 + lt;
            const int b = t / HW_, hw = t - b * HW_;
            const float* src = A0 + ((size_t)b * C_ + (k0 + lc)) * HW_ + hw;
            float4 v0 = *(const float4*)src;
            float4 v1 = *(const float4*)(src + 4);
            float4 m0 = *(const float4*)(mean + t);
            float4 m1 = *(const float4*)(mean + t + 4);
            float4 r0 = *(const float4*)(rstd + t);
            float4 r1 = *(const float4*)(rstd + t + 4);
            const float g = lng[k0 + lc], bb = lnb[k0 + lc];
            As[lc][lt + 0] = (v0.x - m0.x) * r0.x * g + bb;
            As[lc][lt + 1] = (v0.y - m0.y) * r0.y * g + bb;
            As[lc][lt + 2] = (v0.z - m0.z) * r0.z * g + bb;
            As[lc][lt + 3] = (v0.w - m0.w) * r0.w * g + bb;
            As[lc][lt + 4] = (v1.x - m1.x) * r1.x * g + bb;
            As[lc][lt + 5] = (v1.y - m1.y) * r1.y * g + bb;
            As[lc][lt + 6] = (v1.z - m1.z) * r1.z * g + bb;
            As[lc][lt + 7] = (v1.w - m1.w) * r1.w * g + bb;
        } else if (AMODE == A_PLANAR_V) {
            const int lr = tid >> 1;            // row 0..127
            const int lk = (tid & 1) * 8;       // 0 or 8
            const int gr = lda + t0 + lr;       // global (b,w,h) row
            const int b = gr / (W_ * H_);
            const int rem = gr - b * (W_ * H_);
            const int w = rem / H_;
            const int h = rem - w * H_;
            const float* src = A0 + ((size_t)b * HW_ + (size_t)h * W_ + w) * 256
                               + 128 + k0 + lk;
            float4 v0 = *(const float4*)src;
            float4 v1 = *(const float4*)(src + 4);
            As[lk + 0][lr] = v0.x; As[lk + 1][lr] = v0.y;
            As[lk + 2][lr] = v0.z; As[lk + 3][lr] = v0.w;
            As[lk + 4][lr] = v1.x; As[lk + 5][lr] = v1.y;
            As[lk + 6][lr] = v1.z; As[lk + 7][lr] = v1.w;
        } else {
            const int lr = tid >> 1;            // row 0..127
            const int lk = (tid & 1) * 8;       // 0 or 8
            const float* base = A0;
            int kk0 = k0;
            if (AMODE == A_CAT) {
                if (k0 >= 128) { base = A1; kk0 = k0 - 128; }
            }
            const float* src = base + (size_t)(t0 + lr) * lda + kk0 + lk;
            float4 v0 = *(const float4*)src;
            float4 v1 = *(const float4*)(src + 4);
            float vals[8] = {v0.x, v0.y, v0.z, v0.w, v1.x, v1.y, v1.z, v1.w};
            if (AMODE == A_ROW_LN) {
                const float m = mean[t0 + lr], r = rstd[t0 + lr];
                float4 g0 = *(const float4*)(lng + k0 + lk);
                float4 g1 = *(const float4*)(lng + k0 + lk + 4);
                float4 b0 = *(const float4*)(lnb + k0 + lk);
                float4 b1 = *(const float4*)(lnb + k0 + lk + 4);
                float gs[8] = {g0.x, g0.y, g0.z, g0.w, g1.x, g1.y, g1.z, g1.w};
                float bs[8] = {b0.x, b0.y, b0.z, b0.w, b1.x, b1.y, b1.z, b1.w};
                #pragma unroll
                for (int j = 0; j < 8; ++j) vals[j] = (vals[j] - m) * r * gs[j] + bs[j];
            }
            #pragma unroll
            for (int j = 0; j < 8; ++j) As[lk + j][lr] = vals[j];
        }
        // ---- B tile ----
        {
            const int lcol = tid >> 1;
            const int lk = (tid & 1) * 8;
            const float* src = Wt + (size_t)(n0 + lcol) * ldw + k0 + lk;
            float4 w0 = *(const float4*)src;
            float4 w1 = *(const float4*)(src + 4);
            Bs[lk + 0][lcol] = w0.x;
            Bs[lk + 1][lcol] = w0.y;
            Bs[lk + 2][lcol] = w0.z;
            Bs[lk + 3][lcol] = w0.w;
            Bs[lk + 4][lcol] = w1.x;
            Bs[lk + 5][lcol] = w1.y;
            Bs[lk + 6][lcol] = w1.z;
            Bs[lk + 7][lcol] = w1.w;
        }
        __syncthreads();
        #pragma unroll
        for (int kk = 0; kk < BK; ++kk) {
            float4 a0 = *(const float4*)&As[kk][ty * 8];
            float4 a1 = *(const float4*)&As[kk][ty * 8 + 4];
            float4 b0 = *(const float4*)&Bs[kk][tx * 8];
            float4 b1 = *(const float4*)&Bs[kk][tx * 8 + 4];
            float avv[8] = {a0.x, a0.y, a0.z, a0.w, a1.x, a1.y, a1.z, a1.w};
            float bvv[8] = {b0.x, b0.y, b0.z, b0.w, b1.x, b1.y, b1.z, b1.w};
            #pragma unroll
            for (int i = 0; i < 8; ++i)
                #pragma unroll
                for (int j = 0; j < 8; ++j)
                    acc[i][j] += avv[i] * bvv[j];
        }
        __syncthreads();
    }
    // ---- epilogue ----
    const int col = n0 + tx * 8;
    float bb[8];
    {
        float4 bias0 = *(const float4*)(bias + col);
        float4 bias1 = *(const float4*)(bias + col + 4);
        bb[0] = bias0.x; bb[1] = bias0.y; bb[2] = bias0.z; bb[3] = bias0.w;
        bb[4] = bias1.x; bb[5] = bias1.y; bb[6] = bias1.z; bb[7] = bias1.w;
    }
    #pragma unroll
    for (int i = 0; i < 8; ++i) {
        const int row = t0 + ty * 8 + i;
        float v[8];
        #pragma unroll
        for (int j = 0; j < 8; ++j) v[j] = acc[i][j] + bb[j];
        if (EMODE == E_GELU) {
            #pragma unroll
            for (int j = 0; j < 8; ++j)
                v[j] = 0.5f * v[j] * (1.f + erff(v[j] * 0.70710678118654752f));
        }
        if (EMODE == E_FFN2_FIRST) {
            float4 r0 = *(const float4*)(resid + (size_t)row * 256 + col);
            float4 r1 = *(const float4*)(resid + (size_t)row * 256 + col + 4);
            v[0] += r0.x; v[1] += r0.y; v[2] += r0.z; v[3] += r0.w;
            v[4] += r1.x; v[5] += r1.y; v[6] += r1.z; v[7] += r1.w;
        }
        float* dst = out + (size_t)row * ldo + col;
        *(float4*)dst = make_float4(v[0], v[1], v[2], v[3]);
        *(float4*)(dst + 4) = make_float4(v[4], v[5], v[6], v[7]);
    }
}

// x1[t*256+c] += x[(b*C+c)*HW + hw]   (tiled transpose-add, 32 tok x 32 ch)
__global__ __launch_bounds__(256) void tadd_kernel(
    const float* __restrict__ x, float* __restrict__ x1)
{
    __shared__ float tile[32][33];
    int t0 = blockIdx.x * 32;
    int c0 = blockIdx.y * 32;
    int b = t0 / HW_, hw0 = t0 - b * HW_;
    int tid = threadIdx.x;
    int lane = tid & 31, grp = tid >> 5;
    #pragma unroll
    for (int j = 0; j < 4; ++j) {
        int c = grp + j * 8;
        tile[c][lane] = x[((size_t)b * C_ + c0 + c) * HW_ + hw0 + lane];
    }
    __syncthreads();
    #pragma unroll
    for (int j = 0; j < 4; ++j) {
        int tt = grp + j * 8;
        x1[(size_t)(t0 + tt) * C_ + c0 + lane] += tile[lane][tt];
    }
}

// ============================ attention ============================
// one block per (strip, head) within a chunk; online softmax; head dim 16
__global__ __launch_bounds__(256) void attn_h_kernel(
    const float* __restrict__ qkv, float* __restrict__ outb, int strip0)
{
    const int N = 256;
    int head = blockIdx.x & 7;
    int sl = blockIdx.x >> 3;              // strip local to chunk
    int s = strip0 + sl;                   // global strip = b*H + h
    __shared__ float4 Ks[256][4];
    __shared__ float4 Vs[256][4];
    int tid = threadIdx.x;
    const float* base = qkv + (size_t)sl * N * 384;
    {
        const float4* kp = (const float4*)(base + (size_t)tid * 384 + 128 + head * 16);
        Ks[tid][0] = kp[0]; Ks[tid][1] = kp[1]; Ks[tid][2] = kp[2]; Ks[tid][3] = kp[3];
        const float4* vp = (const float4*)(base + (size_t)tid * 384 + 256 + head * 16);
        Vs[tid][0] = vp[0]; Vs[tid][1] = vp[1]; Vs[tid][2] = vp[2]; Vs[tid][3] = vp[3];
    }
    __syncthreads();
    const float4* qp = (const float4*)(base + (size_t)tid * 384 + head * 16);
    float4 q0 = qp[0], q1 = qp[1], q2 = qp[2], q3 = qp[3];
    float mrun = -1e30f, l = 0.f;
    float4 o0 = {0,0,0,0}, o1 = {0,0,0,0}, o2 = {0,0,0,0}, o3 = {0,0,0,0};
    for (int m = 0; m < N; ++m) {
        float4 k0 = Ks[m][0], k1 = Ks[m][1], k2 = Ks[m][2], k3 = Ks[m][3];
        float d0 = q0.x * k0.x + q0.y * k0.y + q0.z * k0.z + q0.w * k0.w;
        float d1 = q1.x * k1.x + q1.y * k1.y + q1.z * k1.z + q1.w * k1.w;
        float d2 = q2.x * k2.x + q2.y * k2.y + q2.z * k2.z + q2.w * k2.w;
        float d3 = q3.x * k3.x + q3.y * k3.y + q3.z * k3.z + q3.w * k3.w;
        float sd = (d0 + d1 + d2 + d3) * 0.25f;
        float mn = fmaxf(mrun, sd);
        float corr = __expf(mrun - mn);
        float p = __expf(sd - mn);
        l = l * corr + p;
        float4 v0 = Vs[m][0], v1 = Vs[m][1], v2 = Vs[m][2], v3 = Vs[m][3];
        o0.x = o0.x * corr + p * v0.x; o0.y = o0.y * corr + p * v0.y;
        o0.z = o0.z * corr + p * v0.z; o0.w = o0.w * corr + p * v0.w;
        o1.x = o1.x * corr + p * v1.x; o1.y = o1.y * corr + p * v1.y;
        o1.z = o1.z * corr + p * v1.z; o1.w = o1.w * corr + p * v1.w;
        o2.x = o2.x * corr + p * v2.x; o2.y = o2.y * corr + p * v2.y;
        o2.z = o2.z * corr + p * v2.z; o2.w = o2.w * corr + p * v2.w;
        o3.x = o3.x * corr + p * v3.x; o3.y = o3.y * corr + p * v3.y;
        o3.z = o3.z * corr + p * v3.z; o3.w = o3.w * corr + p * v3.w;
        mrun = mn;
    }
    float inv = 1.f / l;
    // token = s*W + tid (strip-major [b,h,w])
    float* op = outb + ((size_t)s * W_ + tid) * 128 + head * 16;
    ((float4*)op)[0] = make_float4(o0.x * inv, o0.y * inv, o0.z * inv, o0.w * inv);
    ((float4*)op)[1] = make_float4(o1.x * inv, o1.y * inv, o1.z * inv, o1.w * inv);
    ((float4*)op)[2] = make_float4(o2.x * inv, o2.y * inv, o2.z * inv, o2.w * inv);
    ((float4*)op)[3] = make_float4(o3.x * inv, o3.y * inv, o3.z * inv, o3.w * inv);
}

__global__ __launch_bounds__(192) void attn_v_kernel(
    const float* __restrict__ qkv, float* __restrict__ outb, int strip0)
{
    const int N = 192;
    int head = blockIdx.x & 7;
    int sl = blockIdx.x >> 3;              // strip local to chunk
    int sv = strip0 + sl;                  // global strip = b*W + w
    __shared__ float4 Ks[192][4];
    __shared__ float4 Vs[192][4];
    int tid = threadIdx.x;
    const float* base = qkv + (size_t)sl * N * 384;
    {
        const float4* kp = (const float4*)(base + (size_t)tid * 384 + 128 + head * 16);
        Ks[tid][0] = kp[0]; Ks[tid][1] = kp[1]; Ks[tid][2] = kp[2]; Ks[tid][3] = kp[3];
        const float4* vp = (const float4*)(base + (size_t)tid * 384 + 256 + head * 16);
        Vs[tid][0] = vp[0]; Vs[tid][1] = vp[1]; Vs[tid][2] = vp[2]; Vs[tid][3] = vp[3];
    }
    __syncthreads();
    const float4* qp = (const float4*)(base + (size_t)tid * 384 + head * 16);
    float4 q0 = qp[0], q1 = qp[1], q2 = qp[2], q3 = qp[3];
    float mrun = -1e30f, l = 0.f;
    float4 o0 = {0,0,0,0}, o1 = {0,0,0,0}, o2 = {0,0,0,0}, o3 = {0,0,0,0};
    for (int m = 0; m < N; ++m) {
        float4 k0 = Ks[m][0], k1 = Ks[m][1], k2 = Ks[m][2], k3 = Ks[m][3];
        float d0 = q0.x * k0.x + q0.y * k0.y + q0.z * k0.z + q0.w * k0.w;
        float d1 = q1.x * k1.x + q1.y * k1.y + q1.z * k1.z + q1.w * k1.w;
        float d2 = q2.x * k2.x + q2.y * k2.y + q2.z * k2.z + q2.w * k2.w;
        float d3 = q3.x * k3.x + q3.y * k3.y + q3.z * k3.z + q3.w * k3.w;
        float sd = (d0 + d1 + d2 + d3) * 0.25f;
        float mn = fmaxf(mrun, sd);
        float corr = __expf(mrun - mn);
        float p = __expf(sd - mn);
        l = l * corr + p;
        float4 v0 = Vs[m][0], v1 = Vs[m][1], v2 = Vs[m][2], v3 = Vs[m][3];
        o0.x = o0.x * corr + p * v0.x; o0.y = o0.y * corr + p * v0.y;
        o0.z = o0.z * corr + p * v0.z; o0.w = o0.w * corr + p * v0.w;
        o1.x = o1.x * corr + p * v1.x; o1.y = o1.y * corr + p * v1.y;
        o1.z = o1.z * corr + p * v1.z; o1.w = o1.w * corr + p * v1.w;
        o2.x = o2.x * corr + p * v2.x; o2.y = o2.y * corr + p * v2.y;
        o2.z = o2.z * corr + p * v2.z; o2.w = o2.w * corr + p * v2.w;
        o3.x = o3.x * corr + p * v3.x; o3.y = o3.y * corr + p * v3.y;
        o3.z = o3.z * corr + p * v3.z; o3.w = o3.w * corr + p * v3.w;
        mrun = mn;
    }
    float inv = 1.f / l;
    int b = sv >> 8, w = sv & 255;
    // token = b*HW + tid*W + w   (tid = h)
    float* op = outb + ((size_t)b * HW_ + (size_t)tid * W_ + w) * 128 + head * 16;
    ((float4*)op)[0] = make_float4(o0.x * inv, o0.y * inv, o0.z * inv, o0.w * inv);
    ((float4*)op)[1] = make_float4(o1.x * inv, o1.y * inv, o1.z * inv, o1.w * inv);
    ((float4*)op)[2] = make_float4(o2.x * inv, o2.y * inv, o2.z * inv, o2.w * inv);
    ((float4*)op)[3] = make_float4(o3.x * inv, o3.y * inv, o3.z * inv, o3.w * inv);
}

// ============================ PEG (depthwise 3x3 + residual) ============================
// reads x2 row-major [T,C], writes planar [B,C,H,W] via LDS transpose
__global__ __launch_bounds__(256) void peg_kernel(
    const float* __restrict__ x2t, const float* __restrict__ pw,
    const float* __restrict__ pb, float* __restrict__ outp)
{
    __shared__ float tile[32][33];
    int t0 = blockIdx.x * 32;
    int c0 = blockIdx.y * 32;
    int b = t0 / HW_, hw0 = t0 - b * HW_;
    int tid = threadIdx.x;
    int lane = tid & 31, grp = tid >> 5;
    #pragma unroll
    for (int j = 0; j < 4; ++j) {
        int tt = grp + j * 8;
        int t = t0 + tt;
        int hw = hw0 + tt;
        int h = hw >> 8, w = hw & 255;
        int c = c0 + lane;
        float center = x2t[(size_t)t * C_ + c];
        float acc = center + pb[c];
        #pragma unroll
        for (int dh = -1; dh <= 1; ++dh) {
            int hh = h + dh;
            if (hh < 0 || hh >= H_) continue;
            #pragma unroll
            for (int dw = -1; dw <= 1; ++dw) {
                int ww = w + dw;
                if (ww < 0 || ww >= W_) continue;
                float wgt = pw[c * 9 + (dh + 1) * 3 + (dw + 1)];
                acc += wgt * x2t[(size_t)(t + dh * W_ + dw) * C_ + c];
            }
        }
        tile[lane][tt] = acc;
    }
    __syncthreads();
    #pragma unroll
    for (int j = 0; j < 4; ++j) {
        int cl = grp + j * 8;
        outp[((size_t)b * C_ + c0 + cl) * HW_ + hw0 + lane] = tile[cl][lane];
    }
}

// ============================ launcher ============================
extern "C" void kernel_launch(void* const* d_in, const int* in_sizes, int n_in,
                              void* d_out, int out_size, void* d_ws, size_t ws_size,
                              hipStream_t stream)
{
    (void)in_sizes; (void)n_in; (void)out_size; (void)ws_size;
    const float* x         = (const float*)d_in[0];
    const float* ln1_g     = (const float*)d_in[1];
    const float* ln1_b     = (const float*)d_in[2];
    const float* conv_in_w = (const float*)d_in[3];
    const float* conv_in_b = (const float*)d_in[4];
    const float* qkv_h_w   = (const float*)d_in[5];
    const float* qkv_h_b   = (const float*)d_in[6];
    const float* qkv_v_w   = (const float*)d_in[7];
    const float* qkv_v_b   = (const float*)d_in[8];
    const float* fuse_w    = (const float*)d_in[9];
    const float* fuse_b    = (const float*)d_in[10];
    const float* ln2_g     = (const float*)d_in[11];
    const float* ln2_b     = (const float*)d_in[12];
    const float* fc1_w     = (const float*)d_in[13];
    const float* fc1_b     = (const float*)d_in[14];
    const float* fc2_w     = (const float*)d_in[15];
    const float* fc2_b     = (const float*)d_in[16];
    const float* peg_w     = (const float*)d_in[17];
    const float* peg_b     = (const float*)d_in[18];
    float* outp = (float*)d_out;

    // workspace layout (floats): peak 612*T = ~241 MB
    float* wsf   = (float*)d_ws;
    float* mean1 = wsf;                              // [T]
    float* rstd1 = wsf + (size_t)T_;                 // [T]
    float* mean2 = wsf + 2 * (size_t)T_;             // [T]
    float* rstd2 = wsf + 3 * (size_t)T_;             // [T]
    float* ci    = wsf + 4 * (size_t)T_;             // [T,256]; later x1, then x2
    float* ah    = ci + (size_t)T_ * 256;            // [T,128]; later FFN tmp
    float* av    = ah + (size_t)T_ * 128;            // [T,128]
    float* qkvc  = av + (size_t)T_ * 128;            // [T/4,384] chunk buffer
    float* x1  = ci;
    float* tmp = ah;

    dim3 blk(256);

    // 1. LN1 stats
    ln1_stats_kernel<<<dim3(T_ / 256), blk, 0, stream>>>(x, mean1, rstd1);
    // 2. conv_in: ci = LN1(x) @ conv_in_w^T + b
    gemm_kernel<A_PLANAR_LN, E_BIAS><<<dim3(T_ / 128, 2), blk, 0, stream>>>(
        x, nullptr, conv_in_w, conv_in_b, mean1, rstd1, ln1_g, ln1_b, nullptr, ci,
        256, 0, 256, 256);
    // 3. horizontal: 4 chunks of 96 strips (24576 tokens)
    for (int ch = 0; ch < 4; ++ch) {
        const size_t r0 = (size_t)ch * 24576;
        gemm_kernel<A_ROW, E_BIAS><<<dim3(192, 3), blk, 0, stream>>>(
            ci + r0 * 256, nullptr, qkv_h_w, qkv_h_b, nullptr, nullptr, nullptr,
            nullptr, nullptr, qkvc, 128, 256, 128, 384);
        attn_h_kernel<<<dim3(96 * 8), dim3(256), 0, stream>>>(qkvc, ah, ch * 96);
    }
    // 4. vertical: 4 chunks of 128 strips (24576 rows in (b,w,h) order)
    for (int cv = 0; cv < 4; ++cv) {
        gemm_kernel<A_PLANAR_V, E_BIAS><<<dim3(192, 3), blk, 0, stream>>>(
            ci, nullptr, qkv_v_w, qkv_v_b, nullptr, nullptr, nullptr,
            nullptr, nullptr, qkvc, 128, cv * 24576, 128, 384);
        attn_v_kernel<<<dim3(128 * 8), dim3(192), 0, stream>>>(qkvc, av, cv * 128);
    }
    // 5. fuse: x1 = [ah|av] @ fuse_w^T + fuse_b   (x1 overwrites ci; ci dead)
    gemm_kernel<A_CAT, E_BIAS><<<dim3(T_ / 128, 2), blk, 0, stream>>>(
        ah, av, fuse_w, fuse_b, nullptr, nullptr, nullptr, nullptr, nullptr, x1,
        256, 128, 256, 256);
    // 6. x1 += x (planar residual, tiled transpose-add)
    tadd_kernel<<<dim3(T_ / 32, 8), blk, 0, stream>>>(x, x1);
    // 7. LN2 stats
    ln2_stats_kernel<<<dim3(T_ / 4), blk, 0, stream>>>(x1, mean2, rstd2);
    // 8. FFN: 8 token chunks of 12288 rows; full hidden; in-place x2 over x1
    for (int cs = 0; cs < 8; ++cs) {
        const size_t r0 = (size_t)cs * 12288;
        gemm_kernel<A_ROW_LN, E_GELU><<<dim3(96, 8), blk, 0, stream>>>(
            x1 + r0 * 256, nullptr, fc1_w, fc1_b, mean2 + r0, rstd2 + r0,
            ln2_g, ln2_b, nullptr, tmp, 256, 256, 256, 1024);
        gemm_kernel<A_ROW, E_FFN2_FIRST><<<dim3(96, 2), blk, 0, stream>>>(
            tmp, nullptr, fc2_w, fc2_b, nullptr, nullptr, nullptr, nullptr,
            x1 + r0 * 256, x1 + r0 * 256, 1024, 1024, 1024, 256);
    }
    // 9. PEG + residual -> planar output
    peg_kernel<<<dim3(T_ / 32, 8), blk, 0, stream>>>(x1, peg_w, peg_b, outp);
}

// Round 3
// 1587.217 us; speedup vs baseline: 2.2161x; 2.2161x over previous
//
#include <hip/hip_runtime.h>

#define B_ 2
#define C_ 256
#define H_ 192
#define W_ 256
#define HW_ 49152
#define T_ 98304

typedef __bf16 bf16x8 __attribute__((ext_vector_type(8)));
typedef float  f32x4  __attribute__((ext_vector_type(4)));
typedef short  s16x8  __attribute__((ext_vector_type(8)));

__device__ inline unsigned short f2bf(float f) {
    unsigned u = __float_as_uint(f);
    u = u + 0x7fffu + ((u >> 16) & 1u);
    return (unsigned short)(u >> 16);
}
__device__ inline float bf2f(unsigned short u) {
    return __uint_as_float(((unsigned)u) << 16);
}

// ============================ weight fp32 -> bf16 ============================
__global__ __launch_bounds__(256) void wcvt_kernel(
    const float* __restrict__ in, unsigned short* __restrict__ out, int n)
{
    int i = (blockIdx.x * 256 + threadIdx.x) * 4;
    if (i >= n) return;
    float4 v = *(const float4*)(in + i);
    out[i + 0] = f2bf(v.x);
    out[i + 1] = f2bf(v.y);
    out[i + 2] = f2bf(v.z);
    out[i + 3] = f2bf(v.w);
}

// ============================ LN stats ============================
__global__ __launch_bounds__(256) void ln1_stats_kernel(
    const float* __restrict__ x, float* __restrict__ mean, float* __restrict__ rstd)
{
    int t = blockIdx.x * 256 + threadIdx.x;
    int b = t / HW_;
    int hw = t - b * HW_;
    const float* p = x + (size_t)b * C_ * HW_ + hw;
    float s = 0.f, q = 0.f;
    for (int c = 0; c < C_; ++c) {
        float v = p[(size_t)c * HW_];
        s += v; q += v * v;
    }
    float m = s * (1.f / C_);
    float var = q * (1.f / C_) - m * m;
    mean[t] = m;
    rstd[t] = rsqrtf(var + 1e-5f);
}

__global__ __launch_bounds__(256) void ln2_stats_kernel(
    const float* __restrict__ xr, float* __restrict__ mean, float* __restrict__ rstd)
{
    int wv = threadIdx.x >> 6, lane = threadIdx.x & 63;
    int t = blockIdx.x * 4 + wv;
    const float4 v = *(const float4*)(xr + (size_t)t * C_ + lane * 4);
    float s = v.x + v.y + v.z + v.w;
    float q = v.x * v.x + v.y * v.y + v.z * v.z + v.w * v.w;
    #pragma unroll
    for (int o = 32; o > 0; o >>= 1) {
        s += __shfl_xor(s, o);
        q += __shfl_xor(q, o);
    }
    if (lane == 0) {
        float m = s * (1.f / C_);
        float var = q * (1.f / C_) - m * m;
        mean[t] = m;
        rstd[t] = rsqrtf(var + 1e-5f);
    }
}

// ============================ x -> LN1(x) bf16 row-major ============================
__global__ __launch_bounds__(256) void xln_kernel(
    const float* __restrict__ x, const float* __restrict__ mean,
    const float* __restrict__ rstd, const float* __restrict__ g,
    const float* __restrict__ bta, unsigned short* __restrict__ xn)
{
    __shared__ float tile[32][33];
    int t0 = blockIdx.x * 32;
    int c0 = blockIdx.y * 32;
    int b = t0 / HW_, hw0 = t0 - b * HW_;
    int tid = threadIdx.x, lane = tid & 31, grp = tid >> 5;
    float mm = mean[t0 + lane], rr = rstd[t0 + lane];
    #pragma unroll
    for (int j = 0; j < 4; ++j) {
        int c = grp + j * 8;
        float v = x[((size_t)b * C_ + c0 + c) * HW_ + hw0 + lane];
        tile[c][lane] = (v - mm) * rr;
    }
    __syncthreads();
    float gg = g[c0 + lane], bb = bta[c0 + lane];
    #pragma unroll
    for (int j = 0; j < 4; ++j) {
        int tt = grp + j * 8;
        xn[(size_t)(t0 + tt) * C_ + c0 + lane] = f2bf(tile[lane][tt] * gg + bb);
    }
}

// ============================ MFMA GEMM ============================
// C[M,N] = A[M,K] @ W[N,K]^T (+ epilogue). bf16 inputs, fp32 accumulate.
// 128x128 tile, BK=32, 256 threads = 4 waves (2x2), each wave 4x4 frags of 16x16x32.
// LDS layout: 8 subtiles of 16 rows; subtile s stores lane-major: element
// (row = s*16 + (l&15), k = (l>>4)*8 + j) at shorts [s][l*8 + j] -> every
// fragment ds_read_b128 is lane*16B contiguous (conflict-free).
enum { AB_ROW = 0, AB_CAT = 1, AB_GATHER = 2, AF32_LN = 3 };
enum { EB_BF16 = 0, EB_F32 = 1, EG_BF16 = 2, ER_F32 = 3 };

template<int AMODE, int EMODE>
__global__ __launch_bounds__(256) void mgemm(
    const unsigned short* __restrict__ A0, const unsigned short* __restrict__ A1,
    const float* __restrict__ Af,
    const unsigned short* __restrict__ Wb, const float* __restrict__ bias,
    const float* __restrict__ mean, const float* __restrict__ rstd,
    const float* __restrict__ lng, const float* __restrict__ lnb,
    const float* __restrict__ resid, float* __restrict__ outf,
    unsigned short* __restrict__ outb,
    int K, int lda, int ldw, int ldo, int rowoff)
{
    __shared__ __align__(16) short As[8][512];
    __shared__ __align__(16) short Bs[8][512];
    const int tid = threadIdx.x;
    const int t0 = blockIdx.x * 128;
    const int n0 = blockIdx.y * 128;
    const int lane = tid & 63, wv = tid >> 6;
    const int wr = wv >> 1, wc = wv & 1;

    f32x4 acc[4][4];
    #pragma unroll
    for (int m = 0; m < 4; ++m)
        #pragma unroll
        for (int n = 0; n < 4; ++n)
            acc[m][n] = (f32x4){0.f, 0.f, 0.f, 0.f};

    for (int k0 = 0; k0 < K; k0 += 32) {
        #pragma unroll
        for (int ic = 0; ic < 2; ++ic) {
            const int c = ic * 256 + tid;
            const int r = c >> 2;
            const int kk = (c & 3) * 8;
            const int slot = (((r & 15) | ((kk >> 3) << 4))) * 8;
            // ---- A chunk ----
            s16x8 v;
            if (AMODE == AF32_LN) {
                const float* src = Af + (size_t)(t0 + r) * lda + k0 + kk;
                float4 v0 = *(const float4*)src;
                float4 v1 = *(const float4*)(src + 4);
                const float mm = mean[t0 + r], rr = rstd[t0 + r];
                float4 g0 = *(const float4*)(lng + k0 + kk);
                float4 g1 = *(const float4*)(lng + k0 + kk + 4);
                float4 b0 = *(const float4*)(lnb + k0 + kk);
                float4 b1 = *(const float4*)(lnb + k0 + kk + 4);
                v[0] = (short)f2bf((v0.x - mm) * rr * g0.x + b0.x);
                v[1] = (short)f2bf((v0.y - mm) * rr * g0.y + b0.y);
                v[2] = (short)f2bf((v0.z - mm) * rr * g0.z + b0.z);
                v[3] = (short)f2bf((v0.w - mm) * rr * g0.w + b0.w);
                v[4] = (short)f2bf((v1.x - mm) * rr * g1.x + b1.x);
                v[5] = (short)f2bf((v1.y - mm) * rr * g1.y + b1.y);
                v[6] = (short)f2bf((v1.z - mm) * rr * g1.z + b1.z);
                v[7] = (short)f2bf((v1.w - mm) * rr * g1.w + b1.w);
            } else {
                const unsigned short* src;
                if (AMODE == AB_CAT) {
                    src = (k0 < 128)
                        ? A0 + (size_t)(t0 + r) * 128 + k0 + kk
                        : A1 + (size_t)(t0 + r) * 128 + (k0 - 128) + kk;
                } else if (AMODE == AB_GATHER) {
                    const int gr = rowoff + t0 + r;      // (b, w, h) row
                    const int b = gr / HW_;              // W_*H_ == HW_
                    const int rem = gr - b * HW_;
                    const int w = rem / H_;
                    const int h = rem - w * H_;
                    src = A0 + ((size_t)b * HW_ + (size_t)h * W_ + w) * 256
                          + 128 + k0 + kk;
                } else {
                    src = A0 + (size_t)(t0 + r) * lda + k0 + kk;
                }
                v = *(const s16x8*)src;
            }
            *(s16x8*)&As[r >> 4][slot] = v;
            // ---- B chunk (weights, pre-converted bf16 row-major [N,K]) ----
            s16x8 wv8 = *(const s16x8*)(Wb + (size_t)(n0 + r) * ldw + k0 + kk);
            *(s16x8*)&Bs[r >> 4][slot] = wv8;
        }
        __syncthreads();
        bf16x8 af[4], bfr[4];
        #pragma unroll
        for (int m = 0; m < 4; ++m)
            af[m] = __builtin_bit_cast(bf16x8, *(const s16x8*)&As[wr * 4 + m][lane * 8]);
        #pragma unroll
        for (int n = 0; n < 4; ++n)
            bfr[n] = __builtin_bit_cast(bf16x8, *(const s16x8*)&Bs[wc * 4 + n][lane * 8]);
        #pragma unroll
        for (int m = 0; m < 4; ++m)
            #pragma unroll
            for (int n = 0; n < 4; ++n)
                acc[m][n] = __builtin_amdgcn_mfma_f32_16x16x32_bf16(
                    af[m], bfr[n], acc[m][n], 0, 0, 0);
        __syncthreads();
    }

    // ---- epilogue: lane holds D[(lane>>4)*4 + r][lane&15] per fragment ----
    const int rowb = t0 + wr * 64 + (lane >> 4) * 4;
    const int colb = n0 + wc * 64 + (lane & 15);
    #pragma unroll
    for (int n = 0; n < 4; ++n) {
        const int col = colb + n * 16;
        const float bcol = bias[col];
        #pragma unroll
        for (int m = 0; m < 4; ++m) {
            #pragma unroll
            for (int r = 0; r < 4; ++r) {
                const int row = rowb + m * 16 + r;
                float v = acc[m][n][r] + bcol;
                if (EMODE == EG_BF16)
                    v = 0.5f * v * (1.f + erff(v * 0.70710678118654752f));
                if (EMODE == ER_F32)
                    v += resid[(size_t)row * 256 + col];
                if (EMODE == EB_F32 || EMODE == ER_F32)
                    outf[(size_t)row * ldo + col] = v;
                else
                    outb[(size_t)row * ldo + col] = f2bf(v);
            }
        }
    }
}

// x1[t*256+c] += x[(b*C+c)*HW + hw]   (tiled transpose-add)
__global__ __launch_bounds__(256) void tadd_kernel(
    const float* __restrict__ x, float* __restrict__ x1)
{
    __shared__ float tile[32][33];
    int t0 = blockIdx.x * 32;
    int c0 = blockIdx.y * 32;
    int b = t0 / HW_, hw0 = t0 - b * HW_;
    int tid = threadIdx.x;
    int lane = tid & 31, grp = tid >> 5;
    #pragma unroll
    for (int j = 0; j < 4; ++j) {
        int c = grp + j * 8;
        tile[c][lane] = x[((size_t)b * C_ + c0 + c) * HW_ + hw0 + lane];
    }
    __syncthreads();
    #pragma unroll
    for (int j = 0; j < 4; ++j) {
        int tt = grp + j * 8;
        x1[(size_t)(t0 + tt) * C_ + c0 + lane] += tile[lane][tt];
    }
}

// ============================ attention (bf16 IO) ============================
__global__ __launch_bounds__(256) void attn_h_kernel(
    const unsigned short* __restrict__ qkv, unsigned short* __restrict__ outb, int strip0)
{
    const int N = 256;
    int head = blockIdx.x & 7;
    int sl = blockIdx.x >> 3;
    int s = strip0 + sl;                   // b*H + h
    __shared__ float4 Ks[256][4];
    __shared__ float4 Vs[256][4];
    int tid = threadIdx.x;
    const unsigned short* base = qkv + (size_t)sl * N * 384;
    {
        const s16x8* kp = (const s16x8*)(base + (size_t)tid * 384 + 128 + head * 16);
        s16x8 ka = kp[0], kb = kp[1];
        Ks[tid][0] = make_float4(bf2f(ka[0]), bf2f(ka[1]), bf2f(ka[2]), bf2f(ka[3]));
        Ks[tid][1] = make_float4(bf2f(ka[4]), bf2f(ka[5]), bf2f(ka[6]), bf2f(ka[7]));
        Ks[tid][2] = make_float4(bf2f(kb[0]), bf2f(kb[1]), bf2f(kb[2]), bf2f(kb[3]));
        Ks[tid][3] = make_float4(bf2f(kb[4]), bf2f(kb[5]), bf2f(kb[6]), bf2f(kb[7]));
        const s16x8* vp = (const s16x8*)(base + (size_t)tid * 384 + 256 + head * 16);
        s16x8 va = vp[0], vb = vp[1];
        Vs[tid][0] = make_float4(bf2f(va[0]), bf2f(va[1]), bf2f(va[2]), bf2f(va[3]));
        Vs[tid][1] = make_float4(bf2f(va[4]), bf2f(va[5]), bf2f(va[6]), bf2f(va[7]));
        Vs[tid][2] = make_float4(bf2f(vb[0]), bf2f(vb[1]), bf2f(vb[2]), bf2f(vb[3]));
        Vs[tid][3] = make_float4(bf2f(vb[4]), bf2f(vb[5]), bf2f(vb[6]), bf2f(vb[7]));
    }
    __syncthreads();
    float4 q0, q1, q2, q3;
    {
        const s16x8* qp = (const s16x8*)(base + (size_t)tid * 384 + head * 16);
        s16x8 qa = qp[0], qb = qp[1];
        q0 = make_float4(bf2f(qa[0]), bf2f(qa[1]), bf2f(qa[2]), bf2f(qa[3]));
        q1 = make_float4(bf2f(qa[4]), bf2f(qa[5]), bf2f(qa[6]), bf2f(qa[7]));
        q2 = make_float4(bf2f(qb[0]), bf2f(qb[1]), bf2f(qb[2]), bf2f(qb[3]));
        q3 = make_float4(bf2f(qb[4]), bf2f(qb[5]), bf2f(qb[6]), bf2f(qb[7]));
    }
    float mrun = -1e30f, l = 0.f;
    float4 o0 = {0,0,0,0}, o1 = {0,0,0,0}, o2 = {0,0,0,0}, o3 = {0,0,0,0};
    for (int m = 0; m < N; ++m) {
        float4 k0 = Ks[m][0], k1 = Ks[m][1], k2 = Ks[m][2], k3 = Ks[m][3];
        float d0 = q0.x * k0.x + q0.y * k0.y + q0.z * k0.z + q0.w * k0.w;
        float d1 = q1.x * k1.x + q1.y * k1.y + q1.z * k1.z + q1.w * k1.w;
        float d2 = q2.x * k2.x + q2.y * k2.y + q2.z * k2.z + q2.w * k2.w;
        float d3 = q3.x * k3.x + q3.y * k3.y + q3.z * k3.z + q3.w * k3.w;
        float sd = (d0 + d1 + d2 + d3) * 0.25f;
        float mn = fmaxf(mrun, sd);
        float corr = __expf(mrun - mn);
        float p = __expf(sd - mn);
        l = l * corr + p;
        float4 v0 = Vs[m][0], v1 = Vs[m][1], v2 = Vs[m][2], v3 = Vs[m][3];
        o0.x = o0.x * corr + p * v0.x; o0.y = o0.y * corr + p * v0.y;
        o0.z = o0.z * corr + p * v0.z; o0.w = o0.w * corr + p * v0.w;
        o1.x = o1.x * corr + p * v1.x; o1.y = o1.y * corr + p * v1.y;
        o1.z = o1.z * corr + p * v1.z; o1.w = o1.w * corr + p * v1.w;
        o2.x = o2.x * corr + p * v2.x; o2.y = o2.y * corr + p * v2.y;
        o2.z = o2.z * corr + p * v2.z; o2.w = o2.w * corr + p * v2.w;
        o3.x = o3.x * corr + p * v3.x; o3.y = o3.y * corr + p * v3.y;
        o3.z = o3.z * corr + p * v3.z; o3.w = o3.w * corr + p * v3.w;
        mrun = mn;
    }
    float inv = 1.f / l;
    unsigned short* op = outb + ((size_t)s * W_ + tid) * 128 + head * 16;
    s16x8 lo, hi;
    lo[0] = (short)f2bf(o0.x * inv); lo[1] = (short)f2bf(o0.y * inv);
    lo[2] = (short)f2bf(o0.z * inv); lo[3] = (short)f2bf(o0.w * inv);
    lo[4] = (short)f2bf(o1.x * inv); lo[5] = (short)f2bf(o1.y * inv);
    lo[6] = (short)f2bf(o1.z * inv); lo[7] = (short)f2bf(o1.w * inv);
    hi[0] = (short)f2bf(o2.x * inv); hi[1] = (short)f2bf(o2.y * inv);
    hi[2] = (short)f2bf(o2.z * inv); hi[3] = (short)f2bf(o2.w * inv);
    hi[4] = (short)f2bf(o3.x * inv); hi[5] = (short)f2bf(o3.y * inv);
    hi[6] = (short)f2bf(o3.z * inv); hi[7] = (short)f2bf(o3.w * inv);
    ((s16x8*)op)[0] = lo;
    ((s16x8*)op)[1] = hi;
}

__global__ __launch_bounds__(192) void attn_v_kernel(
    const unsigned short* __restrict__ qkv, unsigned short* __restrict__ outb, int strip0)
{
    const int N = 192;
    int head = blockIdx.x & 7;
    int sl = blockIdx.x >> 3;
    int sv = strip0 + sl;                  // b*W + w
    __shared__ float4 Ks[192][4];
    __shared__ float4 Vs[192][4];
    int tid = threadIdx.x;
    const unsigned short* base = qkv + (size_t)sl * N * 384;
    {
        const s16x8* kp = (const s16x8*)(base + (size_t)tid * 384 + 128 + head * 16);
        s16x8 ka = kp[0], kb = kp[1];
        Ks[tid][0] = make_float4(bf2f(ka[0]), bf2f(ka[1]), bf2f(ka[2]), bf2f(ka[3]));
        Ks[tid][1] = make_float4(bf2f(ka[4]), bf2f(ka[5]), bf2f(ka[6]), bf2f(ka[7]));
        Ks[tid][2] = make_float4(bf2f(kb[0]), bf2f(kb[1]), bf2f(kb[2]), bf2f(kb[3]));
        Ks[tid][3] = make_float4(bf2f(kb[4]), bf2f(kb[5]), bf2f(kb[6]), bf2f(kb[7]));
        const s16x8* vp = (const s16x8*)(base + (size_t)tid * 384 + 256 + head * 16);
        s16x8 va = vp[0], vb = vp[1];
        Vs[tid][0] = make_float4(bf2f(va[0]), bf2f(va[1]), bf2f(va[2]), bf2f(va[3]));
        Vs[tid][1] = make_float4(bf2f(va[4]), bf2f(va[5]), bf2f(va[6]), bf2f(va[7]));
        Vs[tid][2] = make_float4(bf2f(vb[0]), bf2f(vb[1]), bf2f(vb[2]), bf2f(vb[3]));
        Vs[tid][3] = make_float4(bf2f(vb[4]), bf2f(vb[5]), bf2f(vb[6]), bf2f(vb[7]));
    }
    __syncthreads();
    float4 q0, q1, q2, q3;
    {
        const s16x8* qp = (const s16x8*)(base + (size_t)tid * 384 + head * 16);
        s16x8 qa = qp[0], qb = qp[1];
        q0 = make_float4(bf2f(qa[0]), bf2f(qa[1]), bf2f(qa[2]), bf2f(qa[3]));
        q1 = make_float4(bf2f(qa[4]), bf2f(qa[5]), bf2f(qa[6]), bf2f(qa[7]));
        q2 = make_float4(bf2f(qb[0]), bf2f(qb[1]), bf2f(qb[2]), bf2f(qb[3]));
        q3 = make_float4(bf2f(qb[4]), bf2f(qb[5]), bf2f(qb[6]), bf2f(qb[7]));
    }
    float mrun = -1e30f, l = 0.f;
    float4 o0 = {0,0,0,0}, o1 = {0,0,0,0}, o2 = {0,0,0,0}, o3 = {0,0,0,0};
    for (int m = 0; m < N; ++m) {
        float4 k0 = Ks[m][0], k1 = Ks[m][1], k2 = Ks[m][2], k3 = Ks[m][3];
        float d0 = q0.x * k0.x + q0.y * k0.y + q0.z * k0.z + q0.w * k0.w;
        float d1 = q1.x * k1.x + q1.y * k1.y + q1.z * k1.z + q1.w * k1.w;
        float d2 = q2.x * k2.x + q2.y * k2.y + q2.z * k2.z + q2.w * k2.w;
        float d3 = q3.x * k3.x + q3.y * k3.y + q3.z * k3.z + q3.w * k3.w;
        float sd = (d0 + d1 + d2 + d3) * 0.25f;
        float mn = fmaxf(mrun, sd);
        float corr = __expf(mrun - mn);
        float p = __expf(sd - mn);
        l = l * corr + p;
        float4 v0 = Vs[m][0], v1 = Vs[m][1], v2 = Vs[m][2], v3 = Vs[m][3];
        o0.x = o0.x * corr + p * v0.x; o0.y = o0.y * corr + p * v0.y;
        o0.z = o0.z * corr + p * v0.z; o0.w = o0.w * corr + p * v0.w;
        o1.x = o1.x * corr + p * v1.x; o1.y = o1.y * corr + p * v1.y;
        o1.z = o1.z * corr + p * v1.z; o1.w = o1.w * corr + p * v1.w;
        o2.x = o2.x * corr + p * v2.x; o2.y = o2.y * corr + p * v2.y;
        o2.z = o2.z * corr + p * v2.z; o2.w = o2.w * corr + p * v2.w;
        o3.x = o3.x * corr + p * v3.x; o3.y = o3.y * corr + p * v3.y;
        o3.z = o3.z * corr + p * v3.z; o3.w = o3.w * corr + p * v3.w;
        mrun = mn;
    }
    float inv = 1.f / l;
    int b = sv >> 8, w = sv & 255;
    unsigned short* op = outb + ((size_t)b * HW_ + (size_t)tid * W_ + w) * 128 + head * 16;
    s16x8 lo, hi;
    lo[0] = (short)f2bf(o0.x * inv); lo[1] = (short)f2bf(o0.y * inv);
    lo[2] = (short)f2bf(o0.z * inv); lo[3] = (short)f2bf(o0.w * inv);
    lo[4] = (short)f2bf(o1.x * inv); lo[5] = (short)f2bf(o1.y * inv);
    lo[6] = (short)f2bf(o1.z * inv); lo[7] = (short)f2bf(o1.w * inv);
    hi[0] = (short)f2bf(o2.x * inv); hi[1] = (short)f2bf(o2.y * inv);
    hi[2] = (short)f2bf(o2.z * inv); hi[3] = (short)f2bf(o2.w * inv);
    hi[4] = (short)f2bf(o3.x * inv); hi[5] = (short)f2bf(o3.y * inv);
    hi[6] = (short)f2bf(o3.z * inv); hi[7] = (short)f2bf(o3.w * inv);
    ((s16x8*)op)[0] = lo;
    ((s16x8*)op)[1] = hi;
}

// ============================ PEG (depthwise 3x3 + residual) ============================
// tile: 32 tokens x 128 channels; float4 channel vectorization; LDS transpose out
__global__ __launch_bounds__(256) void peg_kernel(
    const float* __restrict__ x2t, const float* __restrict__ pw,
    const float* __restrict__ pb, float* __restrict__ outp)
{
    __shared__ float pwt[9][132];
    __shared__ float tile[128][36];
    const int t0 = blockIdx.x * 32;
    const int cbase = blockIdx.y * 128;
    const int b = t0 / HW_, hw0 = t0 - b * HW_;
    const int h = hw0 >> 8, w0 = hw0 & 255;
    const int tid = threadIdx.x;
    for (int i = tid; i < 1152; i += 256) {
        int tap = i >> 7, ch = i & 127;
        pwt[tap][ch] = pw[(size_t)(cbase + ch) * 9 + tap];
    }
    __syncthreads();
    const int c4 = tid & 31;
    const int tg = tid >> 5;
    const int cq = cbase + c4 * 4;
    float4 pb4 = *(const float4*)(pb + cq);
    #pragma unroll
    for (int j = 0; j < 4; ++j) {
        int tt = tg * 4 + j;
        int t = t0 + tt;
        int w = w0 + tt;
        float4 a = *(const float4*)(x2t + (size_t)t * C_ + cq);
        a.x += pb4.x; a.y += pb4.y; a.z += pb4.z; a.w += pb4.w;
        #pragma unroll
        for (int dh = -1; dh <= 1; ++dh) {
            int hh = h + dh;
            if (hh < 0 || hh >= H_) continue;
            #pragma unroll
            for (int dw = -1; dw <= 1; ++dw) {
                int ww = w + dw;
                if (ww < 0 || ww >= W_) continue;
                float4 xv = *(const float4*)(x2t + (size_t)(t + dh * W_ + dw) * C_ + cq);
                float4 wv = *(const float4*)&pwt[(dh + 1) * 3 + (dw + 1)][c4 * 4];
                a.x += wv.x * xv.x; a.y += wv.y * xv.y;
                a.z += wv.z * xv.z; a.w += wv.w * xv.w;
            }
        }
        tile[c4 * 4 + 0][tt] = a.x;
        tile[c4 * 4 + 1][tt] = a.y;
        tile[c4 * 4 + 2][tt] = a.z;
        tile[c4 * 4 + 3][tt] = a.w;
    }
    __syncthreads();
    const int ch = tid >> 1, hf = (tid & 1) * 16;
    float* drow = outp + ((size_t)b * C_ + cbase + ch) * HW_ + hw0 + hf;
    #pragma unroll
    for (int q = 0; q < 4; ++q) {
        float4 vv = make_float4(tile[ch][hf + q * 4 + 0], tile[ch][hf + q * 4 + 1],
                                tile[ch][hf + q * 4 + 2], tile[ch][hf + q * 4 + 3]);
        *(float4*)(drow + q * 4) = vv;
    }
}

// ============================ launcher ============================
extern "C" void kernel_launch(void* const* d_in, const int* in_sizes, int n_in,
                              void* d_out, int out_size, void* d_ws, size_t ws_size,
                              hipStream_t stream)
{
    (void)in_sizes; (void)n_in; (void)out_size; (void)ws_size;
    const float* x         = (const float*)d_in[0];
    const float* ln1_g     = (const float*)d_in[1];
    const float* ln1_b     = (const float*)d_in[2];
    const float* conv_in_w = (const float*)d_in[3];
    const float* conv_in_b = (const float*)d_in[4];
    const float* qkv_h_w   = (const float*)d_in[5];
    const float* qkv_h_b   = (const float*)d_in[6];
    const float* qkv_v_w   = (const float*)d_in[7];
    const float* qkv_v_b   = (const float*)d_in[8];
    const float* fuse_w    = (const float*)d_in[9];
    const float* fuse_b    = (const float*)d_in[10];
    const float* ln2_g     = (const float*)d_in[11];
    const float* ln2_b     = (const float*)d_in[12];
    const float* fc1_w     = (const float*)d_in[13];
    const float* fc1_b     = (const float*)d_in[14];
    const float* fc2_w     = (const float*)d_in[15];
    const float* fc2_b     = (const float*)d_in[16];
    const float* peg_w     = (const float*)d_in[17];
    const float* peg_b     = (const float*)d_in[18];
    float* outp = (float*)d_out;

    // workspace (~179 MB): x1 (fp32 [T,256]) overlays xn+ci (bf16, dead by fuse)
    float* wsf   = (float*)d_ws;
    float* mean1 = wsf;
    float* rstd1 = wsf + (size_t)T_;
    float* mean2 = wsf + 2 * (size_t)T_;
    float* rstd2 = wsf + 3 * (size_t)T_;
    float* x1    = wsf + 4 * (size_t)T_;                        // [T,256] f32
    unsigned short* xn = (unsigned short*)x1;                   // [T,256] bf16
    unsigned short* ci = (unsigned short*)(x1 + (size_t)T_ * 128); // [T,256] bf16
    unsigned short* ah = (unsigned short*)(x1 + (size_t)T_ * 256); // [T,128] bf16
    unsigned short* av = ah + (size_t)T_ * 128;                 // [T,128] bf16
    unsigned short* qt = av + (size_t)T_ * 128;                 // qkv chunk / ffn tmp
    unsigned short* wb = qt + (size_t)12288 * 1024;             // bf16 weights
    unsigned short* wconv = wb;
    unsigned short* wqh   = wconv + 65536;
    unsigned short* wqv   = wqh + 49152;
    unsigned short* wfu   = wqv + 49152;
    unsigned short* wf1   = wfu + 65536;
    unsigned short* wf2   = wf1 + 262144;

    dim3 blk(256);

    // 0. weights -> bf16
    wcvt_kernel<<<dim3(64), blk, 0, stream>>>(conv_in_w, wconv, 65536);
    wcvt_kernel<<<dim3(48), blk, 0, stream>>>(qkv_h_w, wqh, 49152);
    wcvt_kernel<<<dim3(48), blk, 0, stream>>>(qkv_v_w, wqv, 49152);
    wcvt_kernel<<<dim3(64), blk, 0, stream>>>(fuse_w, wfu, 65536);
    wcvt_kernel<<<dim3(256), blk, 0, stream>>>(fc1_w, wf1, 262144);
    wcvt_kernel<<<dim3(256), blk, 0, stream>>>(fc2_w, wf2, 262144);
    // 1. LN1 stats + normalized bf16 row-major
    ln1_stats_kernel<<<dim3(T_ / 256), blk, 0, stream>>>(x, mean1, rstd1);
    xln_kernel<<<dim3(T_ / 32, 8), blk, 0, stream>>>(x, mean1, rstd1, ln1_g, ln1_b, xn);
    // 2. conv_in: ci = xn @ conv_in_w^T + b  (bf16 out)
    mgemm<AB_ROW, EB_BF16><<<dim3(768, 2), blk, 0, stream>>>(
        xn, nullptr, nullptr, wconv, conv_in_b, nullptr, nullptr, nullptr, nullptr,
        nullptr, nullptr, ci, 256, 256, 256, 256, 0);
    // 3. horizontal: 4 chunks of 96 strips
    for (int ch = 0; ch < 4; ++ch) {
        const size_t r0 = (size_t)ch * 24576;
        mgemm<AB_ROW, EB_BF16><<<dim3(192, 3), blk, 0, stream>>>(
            ci + r0 * 256, nullptr, nullptr, wqh, qkv_h_b, nullptr, nullptr, nullptr,
            nullptr, nullptr, nullptr, qt, 128, 256, 128, 384, 0);
        attn_h_kernel<<<dim3(96 * 8), dim3(256), 0, stream>>>(qt, ah, ch * 96);
    }
    // 4. vertical: 4 chunks of 128 strips (gathered (b,w,h) rows)
    for (int cv = 0; cv < 4; ++cv) {
        mgemm<AB_GATHER, EB_BF16><<<dim3(192, 3), blk, 0, stream>>>(
            ci, nullptr, nullptr, wqv, qkv_v_b, nullptr, nullptr, nullptr,
            nullptr, nullptr, nullptr, qt, 128, 0, 128, 384, cv * 24576);
        attn_v_kernel<<<dim3(128 * 8), dim3(192), 0, stream>>>(qt, av, cv * 128);
    }
    // 5. fuse: x1 = [ah|av] @ fuse_w^T + fuse_b  (fp32 out; overwrites xn/ci)
    mgemm<AB_CAT, EB_F32><<<dim3(768, 2), blk, 0, stream>>>(
        ah, av, nullptr, wfu, fuse_b, nullptr, nullptr, nullptr, nullptr,
        nullptr, x1, nullptr, 256, 128, 256, 256, 0);
    // 6. x1 += x
    tadd_kernel<<<dim3(T_ / 32, 8), blk, 0, stream>>>(x, x1);
    // 7. LN2 stats
    ln2_stats_kernel<<<dim3(T_ / 4), blk, 0, stream>>>(x1, mean2, rstd2);
    // 8. FFN: 8 token chunks of 12288 rows, in-place residual into x1
    for (int cs = 0; cs < 8; ++cs) {
        const size_t r0 = (size_t)cs * 12288;
        mgemm<AF32_LN, EG_BF16><<<dim3(96, 8), blk, 0, stream>>>(
            nullptr, nullptr, x1 + r0 * 256, wf1, fc1_b, mean2 + r0, rstd2 + r0,
            ln2_g, ln2_b, nullptr, nullptr, qt, 256, 256, 256, 1024, 0);
        mgemm<AB_ROW, ER_F32><<<dim3(96, 2), blk, 0, stream>>>(
            qt, nullptr, nullptr, wf2, fc2_b, nullptr, nullptr, nullptr, nullptr,
            x1 + r0 * 256, x1 + r0 * 256, nullptr, 1024, 1024, 1024, 256, 0);
    }
    // 9. PEG + residual -> planar output
    peg_kernel<<<dim3(T_ / 32, 2), blk, 0, stream>>>(x1, peg_w, peg_b, outp);
}

// Round 4
// 1198.460 us; speedup vs baseline: 2.9350x; 1.3244x over previous
//
#include <hip/hip_runtime.h>

#define B_ 2
#define C_ 256
#define H_ 192
#define W_ 256
#define HW_ 49152
#define T_ 98304

typedef __bf16 bf16x8 __attribute__((ext_vector_type(8)));
typedef float  f32x4  __attribute__((ext_vector_type(4)));
typedef short  s16x8  __attribute__((ext_vector_type(8)));

__device__ inline unsigned short f2bf(float f) {
    unsigned u = __float_as_uint(f);
    u = u + 0x7fffu + ((u >> 16) & 1u);
    return (unsigned short)(u >> 16);
}
__device__ inline float bf2f(unsigned short u) {
    return __uint_as_float(((unsigned)u) << 16);
}
__device__ inline unsigned short bfbits(float f) {
    __bf16 h = (__bf16)f;
    return __builtin_bit_cast(unsigned short, h);
}

// ============================ weight fp32 -> bf16 ============================
__global__ __launch_bounds__(256) void wcvt_kernel(
    const float* __restrict__ in, unsigned short* __restrict__ out, int n)
{
    int i = (blockIdx.x * 256 + threadIdx.x) * 4;
    if (i >= n) return;
    float4 v = *(const float4*)(in + i);
    out[i + 0] = f2bf(v.x);
    out[i + 1] = f2bf(v.y);
    out[i + 2] = f2bf(v.z);
    out[i + 3] = f2bf(v.w);
}

// ============================ LN stats ============================
__global__ __launch_bounds__(256) void ln1_stats_kernel(
    const float* __restrict__ x, float* __restrict__ mean, float* __restrict__ rstd)
{
    int t = blockIdx.x * 256 + threadIdx.x;
    int b = t / HW_;
    int hw = t - b * HW_;
    const float* p = x + (size_t)b * C_ * HW_ + hw;
    float s = 0.f, q = 0.f;
    for (int c = 0; c < C_; ++c) {
        float v = p[(size_t)c * HW_];
        s += v; q += v * v;
    }
    float m = s * (1.f / C_);
    float var = q * (1.f / C_) - m * m;
    mean[t] = m;
    rstd[t] = rsqrtf(var + 1e-5f);
}

__global__ __launch_bounds__(256) void ln2_stats_kernel(
    const float* __restrict__ xr, float* __restrict__ mean, float* __restrict__ rstd)
{
    int wv = threadIdx.x >> 6, lane = threadIdx.x & 63;
    int t = blockIdx.x * 4 + wv;
    const float4 v = *(const float4*)(xr + (size_t)t * C_ + lane * 4);
    float s = v.x + v.y + v.z + v.w;
    float q = v.x * v.x + v.y * v.y + v.z * v.z + v.w * v.w;
    #pragma unroll
    for (int o = 32; o > 0; o >>= 1) {
        s += __shfl_xor(s, o);
        q += __shfl_xor(q, o);
    }
    if (lane == 0) {
        float m = s * (1.f / C_);
        float var = q * (1.f / C_) - m * m;
        mean[t] = m;
        rstd[t] = rsqrtf(var + 1e-5f);
    }
}

// ============================ x -> LN1(x) bf16 row-major ============================
__global__ __launch_bounds__(256) void xln_kernel(
    const float* __restrict__ x, const float* __restrict__ mean,
    const float* __restrict__ rstd, const float* __restrict__ g,
    const float* __restrict__ bta, unsigned short* __restrict__ xn)
{
    __shared__ float tile[32][33];
    int t0 = blockIdx.x * 32;
    int c0 = blockIdx.y * 32;
    int b = t0 / HW_, hw0 = t0 - b * HW_;
    int tid = threadIdx.x, lane = tid & 31, grp = tid >> 5;
    float mm = mean[t0 + lane], rr = rstd[t0 + lane];
    #pragma unroll
    for (int j = 0; j < 4; ++j) {
        int c = grp + j * 8;
        float v = x[((size_t)b * C_ + c0 + c) * HW_ + hw0 + lane];
        tile[c][lane] = (v - mm) * rr;
    }
    __syncthreads();
    float gg = g[c0 + lane], bb = bta[c0 + lane];
    #pragma unroll
    for (int j = 0; j < 4; ++j) {
        int tt = grp + j * 8;
        xn[(size_t)(t0 + tt) * C_ + c0 + lane] = f2bf(tile[lane][tt] * gg + bb);
    }
}

// ============================ MFMA GEMM ============================
enum { AB_ROW = 0, AB_CAT = 1, AB_GATHER = 2, AF32_LN = 3 };
enum { EB_BF16 = 0, EB_F32 = 1, EG_BF16 = 2, ER_F32 = 3 };

template<int AMODE, int EMODE>
__global__ __launch_bounds__(256) void mgemm(
    const unsigned short* __restrict__ A0, const unsigned short* __restrict__ A1,
    const float* __restrict__ Af,
    const unsigned short* __restrict__ Wb, const float* __restrict__ bias,
    const float* __restrict__ mean, const float* __restrict__ rstd,
    const float* __restrict__ lng, const float* __restrict__ lnb,
    const float* __restrict__ resid, float* __restrict__ outf,
    unsigned short* __restrict__ outb,
    int K, int lda, int ldw, int ldo, int rowoff)
{
    __shared__ __align__(16) short As[8][512];
    __shared__ __align__(16) short Bs[8][512];
    const int tid = threadIdx.x;
    const int t0 = blockIdx.x * 128;
    const int n0 = blockIdx.y * 128;
    const int lane = tid & 63, wv = tid >> 6;
    const int wr = wv >> 1, wc = wv & 1;

    f32x4 acc[4][4];
    #pragma unroll
    for (int m = 0; m < 4; ++m)
        #pragma unroll
        for (int n = 0; n < 4; ++n)
            acc[m][n] = (f32x4){0.f, 0.f, 0.f, 0.f};

    for (int k0 = 0; k0 < K; k0 += 32) {
        #pragma unroll
        for (int ic = 0; ic < 2; ++ic) {
            const int c = ic * 256 + tid;
            const int r = c >> 2;
            const int kk = (c & 3) * 8;
            const int slot = (((r & 15) | ((kk >> 3) << 4))) * 8;
            s16x8 v;
            if (AMODE == AF32_LN) {
                const float* src = Af + (size_t)(t0 + r) * lda + k0 + kk;
                float4 v0 = *(const float4*)src;
                float4 v1 = *(const float4*)(src + 4);
                const float mm = mean[t0 + r], rr = rstd[t0 + r];
                float4 g0 = *(const float4*)(lng + k0 + kk);
                float4 g1 = *(const float4*)(lng + k0 + kk + 4);
                float4 b0 = *(const float4*)(lnb + k0 + kk);
                float4 b1 = *(const float4*)(lnb + k0 + kk + 4);
                v[0] = (short)f2bf((v0.x - mm) * rr * g0.x + b0.x);
                v[1] = (short)f2bf((v0.y - mm) * rr * g0.y + b0.y);
                v[2] = (short)f2bf((v0.z - mm) * rr * g0.z + b0.z);
                v[3] = (short)f2bf((v0.w - mm) * rr * g0.w + b0.w);
                v[4] = (short)f2bf((v1.x - mm) * rr * g1.x + b1.x);
                v[5] = (short)f2bf((v1.y - mm) * rr * g1.y + b1.y);
                v[6] = (short)f2bf((v1.z - mm) * rr * g1.z + b1.z);
                v[7] = (short)f2bf((v1.w - mm) * rr * g1.w + b1.w);
            } else {
                const unsigned short* src;
                if (AMODE == AB_CAT) {
                    src = (k0 < 128)
                        ? A0 + (size_t)(t0 + r) * 128 + k0 + kk
                        : A1 + (size_t)(t0 + r) * 128 + (k0 - 128) + kk;
                } else if (AMODE == AB_GATHER) {
                    const int gr = rowoff + t0 + r;      // (b, w, h) row
                    const int b = gr / HW_;
                    const int rem = gr - b * HW_;
                    const int w = rem / H_;
                    const int h = rem - w * H_;
                    src = A0 + ((size_t)b * HW_ + (size_t)h * W_ + w) * 256
                          + 128 + k0 + kk;
                } else {
                    src = A0 + (size_t)(t0 + r) * lda + k0 + kk;
                }
                v = *(const s16x8*)src;
            }
            *(s16x8*)&As[r >> 4][slot] = v;
            s16x8 wv8 = *(const s16x8*)(Wb + (size_t)(n0 + r) * ldw + k0 + kk);
            *(s16x8*)&Bs[r >> 4][slot] = wv8;
        }
        __syncthreads();
        bf16x8 af[4], bfr[4];
        #pragma unroll
        for (int m = 0; m < 4; ++m)
            af[m] = __builtin_bit_cast(bf16x8, *(const s16x8*)&As[wr * 4 + m][lane * 8]);
        #pragma unroll
        for (int n = 0; n < 4; ++n)
            bfr[n] = __builtin_bit_cast(bf16x8, *(const s16x8*)&Bs[wc * 4 + n][lane * 8]);
        #pragma unroll
        for (int m = 0; m < 4; ++m)
            #pragma unroll
            for (int n = 0; n < 4; ++n)
                acc[m][n] = __builtin_amdgcn_mfma_f32_16x16x32_bf16(
                    af[m], bfr[n], acc[m][n], 0, 0, 0);
        __syncthreads();
    }

    const int rowb = t0 + wr * 64 + (lane >> 4) * 4;
    const int colb = n0 + wc * 64 + (lane & 15);
    #pragma unroll
    for (int n = 0; n < 4; ++n) {
        const int col = colb + n * 16;
        const float bcol = bias[col];
        #pragma unroll
        for (int m = 0; m < 4; ++m) {
            #pragma unroll
            for (int r = 0; r < 4; ++r) {
                const int row = rowb + m * 16 + r;
                float v = acc[m][n][r] + bcol;
                if (EMODE == EG_BF16)
                    v = 0.5f * v * (1.f + erff(v * 0.70710678118654752f));
                if (EMODE == ER_F32)
                    v += resid[(size_t)row * 256 + col];
                if (EMODE == EB_F32 || EMODE == ER_F32)
                    outf[(size_t)row * ldo + col] = v;
                else
                    outb[(size_t)row * ldo + col] = f2bf(v);
            }
        }
    }
}

// x1[t*256+c] += x[(b*C+c)*HW + hw]
__global__ __launch_bounds__(256) void tadd_kernel(
    const float* __restrict__ x, float* __restrict__ x1)
{
    __shared__ float tile[32][33];
    int t0 = blockIdx.x * 32;
    int c0 = blockIdx.y * 32;
    int b = t0 / HW_, hw0 = t0 - b * HW_;
    int tid = threadIdx.x;
    int lane = tid & 31, grp = tid >> 5;
    #pragma unroll
    for (int j = 0; j < 4; ++j) {
        int c = grp + j * 8;
        tile[c][lane] = x[((size_t)b * C_ + c0 + c) * HW_ + hw0 + lane];
    }
    __syncthreads();
    #pragma unroll
    for (int j = 0; j < 4; ++j) {
        int tt = grp + j * 8;
        x1[(size_t)(t0 + tt) * C_ + c0 + lane] += tile[lane][tt];
    }
}

// ============================ MFMA flash attention ============================
// One block per (strip, head); 4 waves, each owns N/4 query rows.
// S^T tiles: mfma(A=K[16rows x d(pad32)], B=Q[16q x d(pad32)]) -> C col=q, row=krow.
// Softmax per q fully lane-local + 2 shfl_xor. P (bf16) -> wave-private LDS slab,
// then O^T = mfma(A=V^T chunk, B=P^T chunk) accumulated over N.
// DIR 0: horizontal (out token = s*W + q). DIR 1: vertical (out token = b*HW + q*W + w).
template<int N, int DIR>
__global__ __launch_bounds__(256) void attn_mfma_kernel(
    const unsigned short* __restrict__ qkv, unsigned short* __restrict__ outb, int strip0)
{
    constexpr int NT = N / 16;       // score tiles along seq
    constexpr int CH = N / 32;       // PV k-chunks
    constexpr int QTW = N / 64;      // Q-tiles per wave
    constexpr int PST = N + 8;       // P row stride (shorts, 16B aligned)
    __shared__ __align__(16) short kls[NT * 256];
    __shared__ __align__(16) short vls[CH * 512];
    __shared__ __align__(16) short plds[4 * 16 * PST];
    const int head = blockIdx.x & 7;
    const int sl = blockIdx.x >> 3;
    const int s = strip0 + sl;
    const int tid = threadIdx.x;
    const unsigned short* base = qkv + (size_t)sl * N * 384;
    // ---- stage K: kls[sub][ (hf*16 + (r&15))*8 + j ] = K[r][hf*8+j]
    for (int i = tid; i < 2 * N; i += 256) {
        int r = i >> 1, hf = i & 1;
        s16x8 kv = *(const s16x8*)(base + (size_t)r * 384 + 128 + head * 16 + hf * 8);
        *(s16x8*)&kls[(r >> 4) * 256 + (hf * 16 + (r & 15)) * 8] = kv;
    }
    // ---- stage V^T: vls[c*512 + ((k'>>3)*16 + d)*8 + (k'&7)] = V[32c+k'][d]
    for (int i = tid; i < 2 * N; i += 256) {
        int r = i >> 1, hf = i & 1;
        s16x8 vv = *(const s16x8*)(base + (size_t)r * 384 + 256 + head * 16 + hf * 8);
        short* dst = &vls[(r >> 5) * 512 + ((r & 31) >> 3) * 128 + (r & 7)];
        #pragma unroll
        for (int j = 0; j < 8; ++j)
            dst[(hf * 8 + j) * 8] = vv[j];
    }
    __syncthreads();
    const int wv = tid >> 6, lane = tid & 63, g = lane >> 4, q = lane & 15;
    short* myP = &plds[wv * 16 * PST];
    const bf16x8 zf = __builtin_bit_cast(bf16x8, (s16x8){0,0,0,0,0,0,0,0});
    for (int qt_i = 0; qt_i < QTW; ++qt_i) {
        const int q0 = wv * (N / 4) + qt_i * 16;
        bf16x8 qf = zf;
        if (lane < 32)
            qf = __builtin_bit_cast(bf16x8,
                *(const s16x8*)(base + (size_t)(q0 + q) * 384 + head * 16 + g * 8));
        f32x4 sc[NT];
        #pragma unroll
        for (int n = 0; n < NT; ++n) {
            bf16x8 kf = zf;
            if (lane < 32)
                kf = __builtin_bit_cast(bf16x8, *(const s16x8*)&kls[n * 256 + lane * 8]);
            sc[n] = __builtin_amdgcn_mfma_f32_16x16x32_bf16(
                kf, qf, (f32x4){0.f, 0.f, 0.f, 0.f}, 0, 0, 0);
        }
        // row max (all 4 regs of every tile belong to row q of this lane)
        float mx = -3.0e38f;
        #pragma unroll
        for (int n = 0; n < NT; ++n)
            mx = fmaxf(mx, fmaxf(fmaxf(sc[n][0], sc[n][1]), fmaxf(sc[n][2], sc[n][3])));
        mx = fmaxf(mx, __shfl_xor(mx, 16));
        mx = fmaxf(mx, __shfl_xor(mx, 32));
        // exp, sum, write P (bf16) to wave-private LDS
        float sum = 0.f;
        #pragma unroll
        for (int n = 0; n < NT; ++n) {
            float p0 = __expf((sc[n][0] - mx) * 0.25f);
            float p1 = __expf((sc[n][1] - mx) * 0.25f);
            float p2 = __expf((sc[n][2] - mx) * 0.25f);
            float p3 = __expf((sc[n][3] - mx) * 0.25f);
            sum += (p0 + p1) + (p2 + p3);
            unsigned u01 = ((unsigned)bfbits(p1) << 16) | bfbits(p0);
            unsigned u23 = ((unsigned)bfbits(p3) << 16) | bfbits(p2);
            *(unsigned*)&myP[q * PST + n * 16 + g * 4] = u01;
            *(unsigned*)&myP[q * PST + n * 16 + g * 4 + 2] = u23;
        }
        sum += __shfl_xor(sum, 16);
        sum += __shfl_xor(sum, 32);
        const float inv = 1.f / sum;
        // PV: O^T accumulate
        f32x4 o = (f32x4){0.f, 0.f, 0.f, 0.f};
        #pragma unroll
        for (int c = 0; c < CH; ++c) {
            bf16x8 vf = __builtin_bit_cast(bf16x8, *(const s16x8*)&vls[c * 512 + lane * 8]);
            bf16x8 pf = __builtin_bit_cast(bf16x8, *(const s16x8*)&myP[q * PST + c * 32 + g * 8]);
            o = __builtin_amdgcn_mfma_f32_16x16x32_bf16(vf, pf, o, 0, 0, 0);
        }
        // store O[q][d = g*4 + r]
        unsigned lo = ((unsigned)bfbits(o[1] * inv) << 16) | bfbits(o[0] * inv);
        unsigned hi = ((unsigned)bfbits(o[3] * inv) << 16) | bfbits(o[2] * inv);
        size_t dst;
        if (DIR == 0) {
            dst = ((size_t)s * W_ + q0 + q) * 128 + head * 16 + g * 4;
        } else {
            int b = s >> 8, w = s & 255;
            dst = ((size_t)b * HW_ + (size_t)(q0 + q) * W_ + w) * 128 + head * 16 + g * 4;
        }
        *(uint2*)&outb[dst] = make_uint2(lo, hi);
    }
}

// ============================ PEG (depthwise 3x3 + residual) ============================
__global__ __launch_bounds__(256) void peg_kernel(
    const float* __restrict__ x2t, const float* __restrict__ pw,
    const float* __restrict__ pb, float* __restrict__ outp)
{
    __shared__ float pwt[9][132];
    __shared__ float tile[128][36];
    const int t0 = blockIdx.x * 32;
    const int cbase = blockIdx.y * 128;
    const int b = t0 / HW_, hw0 = t0 - b * HW_;
    const int h = hw0 >> 8, w0 = hw0 & 255;
    const int tid = threadIdx.x;
    for (int i = tid; i < 1152; i += 256) {
        int tap = i >> 7, ch = i & 127;
        pwt[tap][ch] = pw[(size_t)(cbase + ch) * 9 + tap];
    }
    __syncthreads();
    const int c4 = tid & 31;
    const int tg = tid >> 5;
    const int cq = cbase + c4 * 4;
    float4 pb4 = *(const float4*)(pb + cq);
    #pragma unroll
    for (int j = 0; j < 4; ++j) {
        int tt = tg * 4 + j;
        int t = t0 + tt;
        int w = w0 + tt;
        float4 a = *(const float4*)(x2t + (size_t)t * C_ + cq);
        a.x += pb4.x; a.y += pb4.y; a.z += pb4.z; a.w += pb4.w;
        #pragma unroll
        for (int dh = -1; dh <= 1; ++dh) {
            int hh = h + dh;
            if (hh < 0 || hh >= H_) continue;
            #pragma unroll
            for (int dw = -1; dw <= 1; ++dw) {
                int ww = w + dw;
                if (ww < 0 || ww >= W_) continue;
                float4 xv = *(const float4*)(x2t + (size_t)(t + dh * W_ + dw) * C_ + cq);
                float4 wv = *(const float4*)&pwt[(dh + 1) * 3 + (dw + 1)][c4 * 4];
                a.x += wv.x * xv.x; a.y += wv.y * xv.y;
                a.z += wv.z * xv.z; a.w += wv.w * xv.w;
            }
        }
        tile[c4 * 4 + 0][tt] = a.x;
        tile[c4 * 4 + 1][tt] = a.y;
        tile[c4 * 4 + 2][tt] = a.z;
        tile[c4 * 4 + 3][tt] = a.w;
    }
    __syncthreads();
    const int ch = tid >> 1, hf = (tid & 1) * 16;
    float* drow = outp + ((size_t)b * C_ + cbase + ch) * HW_ + hw0 + hf;
    #pragma unroll
    for (int qq = 0; qq < 4; ++qq) {
        float4 vv = make_float4(tile[ch][hf + qq * 4 + 0], tile[ch][hf + qq * 4 + 1],
                                tile[ch][hf + qq * 4 + 2], tile[ch][hf + qq * 4 + 3]);
        *(float4*)(drow + qq * 4) = vv;
    }
}

// ============================ launcher ============================
extern "C" void kernel_launch(void* const* d_in, const int* in_sizes, int n_in,
                              void* d_out, int out_size, void* d_ws, size_t ws_size,
                              hipStream_t stream)
{
    (void)in_sizes; (void)n_in; (void)out_size; (void)ws_size;
    const float* x         = (const float*)d_in[0];
    const float* ln1_g     = (const float*)d_in[1];
    const float* ln1_b     = (const float*)d_in[2];
    const float* conv_in_w = (const float*)d_in[3];
    const float* conv_in_b = (const float*)d_in[4];
    const float* qkv_h_w   = (const float*)d_in[5];
    const float* qkv_h_b   = (const float*)d_in[6];
    const float* qkv_v_w   = (const float*)d_in[7];
    const float* qkv_v_b   = (const float*)d_in[8];
    const float* fuse_w    = (const float*)d_in[9];
    const float* fuse_b    = (const float*)d_in[10];
    const float* ln2_g     = (const float*)d_in[11];
    const float* ln2_b     = (const float*)d_in[12];
    const float* fc1_w     = (const float*)d_in[13];
    const float* fc1_b     = (const float*)d_in[14];
    const float* fc2_w     = (const float*)d_in[15];
    const float* fc2_b     = (const float*)d_in[16];
    const float* peg_w     = (const float*)d_in[17];
    const float* peg_b     = (const float*)d_in[18];
    float* outp = (float*)d_out;

    float* wsf   = (float*)d_ws;
    float* mean1 = wsf;
    float* rstd1 = wsf + (size_t)T_;
    float* mean2 = wsf + 2 * (size_t)T_;
    float* rstd2 = wsf + 3 * (size_t)T_;
    float* x1    = wsf + 4 * (size_t)T_;                           // [T,256] f32
    unsigned short* xn = (unsigned short*)x1;                      // [T,256] bf16
    unsigned short* ci = (unsigned short*)(x1 + (size_t)T_ * 128); // [T,256] bf16
    unsigned short* ah = (unsigned short*)(x1 + (size_t)T_ * 256); // [T,128] bf16
    unsigned short* av = ah + (size_t)T_ * 128;                    // [T,128] bf16
    unsigned short* qt = av + (size_t)T_ * 128;                    // qkv chunk / ffn tmp
    unsigned short* wb = qt + (size_t)12288 * 1024;
    unsigned short* wconv = wb;
    unsigned short* wqh   = wconv + 65536;
    unsigned short* wqv   = wqh + 49152;
    unsigned short* wfu   = wqv + 49152;
    unsigned short* wf1   = wfu + 65536;
    unsigned short* wf2   = wf1 + 262144;

    dim3 blk(256);

    wcvt_kernel<<<dim3(64), blk, 0, stream>>>(conv_in_w, wconv, 65536);
    wcvt_kernel<<<dim3(48), blk, 0, stream>>>(qkv_h_w, wqh, 49152);
    wcvt_kernel<<<dim3(48), blk, 0, stream>>>(qkv_v_w, wqv, 49152);
    wcvt_kernel<<<dim3(64), blk, 0, stream>>>(fuse_w, wfu, 65536);
    wcvt_kernel<<<dim3(256), blk, 0, stream>>>(fc1_w, wf1, 262144);
    wcvt_kernel<<<dim3(256), blk, 0, stream>>>(fc2_w, wf2, 262144);
    // 1. LN1 stats + normalized bf16 row-major
    ln1_stats_kernel<<<dim3(T_ / 256), blk, 0, stream>>>(x, mean1, rstd1);
    xln_kernel<<<dim3(T_ / 32, 8), blk, 0, stream>>>(x, mean1, rstd1, ln1_g, ln1_b, xn);
    // 2. conv_in
    mgemm<AB_ROW, EB_BF16><<<dim3(768, 2), blk, 0, stream>>>(
        xn, nullptr, nullptr, wconv, conv_in_b, nullptr, nullptr, nullptr, nullptr,
        nullptr, nullptr, ci, 256, 256, 256, 256, 0);
    // 3. horizontal attention: 4 chunks of 96 strips
    for (int ch = 0; ch < 4; ++ch) {
        const size_t r0 = (size_t)ch * 24576;
        mgemm<AB_ROW, EB_BF16><<<dim3(192, 3), blk, 0, stream>>>(
            ci + r0 * 256, nullptr, nullptr, wqh, qkv_h_b, nullptr, nullptr, nullptr,
            nullptr, nullptr, nullptr, qt, 128, 256, 128, 384, 0);
        attn_mfma_kernel<256, 0><<<dim3(96 * 8), blk, 0, stream>>>(qt, ah, ch * 96);
    }
    // 4. vertical attention: 4 chunks of 128 strips
    for (int cv = 0; cv < 4; ++cv) {
        mgemm<AB_GATHER, EB_BF16><<<dim3(192, 3), blk, 0, stream>>>(
            ci, nullptr, nullptr, wqv, qkv_v_b, nullptr, nullptr, nullptr,
            nullptr, nullptr, nullptr, qt, 128, 0, 128, 384, cv * 24576);
        attn_mfma_kernel<192, 1><<<dim3(128 * 8), blk, 0, stream>>>(qt, av, cv * 128);
    }
    // 5. fuse
    mgemm<AB_CAT, EB_F32><<<dim3(768, 2), blk, 0, stream>>>(
        ah, av, nullptr, wfu, fuse_b, nullptr, nullptr, nullptr, nullptr,
        nullptr, x1, nullptr, 256, 128, 256, 256, 0);
    // 6. x1 += x
    tadd_kernel<<<dim3(T_ / 32, 8), blk, 0, stream>>>(x, x1);
    // 7. LN2 stats
    ln2_stats_kernel<<<dim3(T_ / 4), blk, 0, stream>>>(x1, mean2, rstd2);
    // 8. FFN: 8 token chunks, in-place residual into x1
    for (int cs = 0; cs < 8; ++cs) {
        const size_t r0 = (size_t)cs * 12288;
        mgemm<AF32_LN, EG_BF16><<<dim3(96, 8), blk, 0, stream>>>(
            nullptr, nullptr, x1 + r0 * 256, wf1, fc1_b, mean2 + r0, rstd2 + r0,
            ln2_g, ln2_b, nullptr, nullptr, qt, 256, 256, 256, 1024, 0);
        mgemm<AB_ROW, ER_F32><<<dim3(96, 2), blk, 0, stream>>>(
            qt, nullptr, nullptr, wf2, fc2_b, nullptr, nullptr, nullptr, nullptr,
            x1 + r0 * 256, x1 + r0 * 256, nullptr, 1024, 1024, 1024, 256, 0);
    }
    // 9. PEG + residual -> planar output
    peg_kernel<<<dim3(T_ / 32, 2), blk, 0, stream>>>(x1, peg_w, peg_b, outp);
}

// Round 5
// 1074.755 us; speedup vs baseline: 3.2728x; 1.1151x over previous
//
#include <hip/hip_runtime.h>

#define B_ 2
#define C_ 256
#define H_ 192
#define W_ 256
#define HW_ 49152
#define T_ 98304

typedef __bf16 bf16x8 __attribute__((ext_vector_type(8)));
typedef float  f32x4  __attribute__((ext_vector_type(4)));
typedef short  s16x8  __attribute__((ext_vector_type(8)));

__device__ inline unsigned short f2bf(float f) {
    unsigned u = __float_as_uint(f);
    u = u + 0x7fffu + ((u >> 16) & 1u);
    return (unsigned short)(u >> 16);
}
__device__ inline float bf2f(unsigned short u) {
    return __uint_as_float(((unsigned)u) << 16);
}
__device__ inline unsigned short bfbits(float f) {
    __bf16 h = (__bf16)f;
    return __builtin_bit_cast(unsigned short, h);
}
// async global->LDS, 16B per lane; LDS dest = base + lane*16 (HW rule)
__device__ inline void gload_lds16(const unsigned short* g, short* l) {
    __builtin_amdgcn_global_load_lds(
        (const __attribute__((address_space(1))) unsigned int*)g,
        (__attribute__((address_space(3))) unsigned int*)l, 16, 0, 0);
}

// ============================ weight fp32 -> bf16 ============================
__global__ __launch_bounds__(256) void wcvt_kernel(
    const float* __restrict__ in, unsigned short* __restrict__ out, int n)
{
    int i = (blockIdx.x * 256 + threadIdx.x) * 4;
    if (i >= n) return;
    float4 v = *(const float4*)(in + i);
    out[i + 0] = f2bf(v.x);
    out[i + 1] = f2bf(v.y);
    out[i + 2] = f2bf(v.z);
    out[i + 3] = f2bf(v.w);
}

// ============================ LN1 stats ============================
__global__ __launch_bounds__(256) void ln1_stats_kernel(
    const float* __restrict__ x, float* __restrict__ mean, float* __restrict__ rstd)
{
    int t = blockIdx.x * 256 + threadIdx.x;
    int b = t / HW_;
    int hw = t - b * HW_;
    const float* p = x + (size_t)b * C_ * HW_ + hw;
    float s = 0.f, q = 0.f;
    for (int c = 0; c < C_; ++c) {
        float v = p[(size_t)c * HW_];
        s += v; q += v * v;
    }
    float m = s * (1.f / C_);
    float var = q * (1.f / C_) - m * m;
    mean[t] = m;
    rstd[t] = rsqrtf(var + 1e-5f);
}

// ============================ x -> LN1(x) bf16 row-major ============================
__global__ __launch_bounds__(256) void xln_kernel(
    const float* __restrict__ x, const float* __restrict__ mean,
    const float* __restrict__ rstd, const float* __restrict__ g,
    const float* __restrict__ bta, unsigned short* __restrict__ xn)
{
    __shared__ float tile[32][33];
    int t0 = blockIdx.x * 32;
    int c0 = blockIdx.y * 32;
    int b = t0 / HW_, hw0 = t0 - b * HW_;
    int tid = threadIdx.x, lane = tid & 31, grp = tid >> 5;
    float mm = mean[t0 + lane], rr = rstd[t0 + lane];
    #pragma unroll
    for (int j = 0; j < 4; ++j) {
        int c = grp + j * 8;
        float v = x[((size_t)b * C_ + c0 + c) * HW_ + hw0 + lane];
        tile[c][lane] = (v - mm) * rr;
    }
    __syncthreads();
    float gg = g[c0 + lane], bb = bta[c0 + lane];
    #pragma unroll
    for (int j = 0; j < 4; ++j) {
        int tt = grp + j * 8;
        xn[(size_t)(t0 + tt) * C_ + c0 + lane] = f2bf(tile[lane][tt] * gg + bb);
    }
}

// ============================ LN2: fused stats + normalize -> bf16 ============================
__global__ __launch_bounds__(256) void ln2norm_kernel(
    const float* __restrict__ xr, const float* __restrict__ g,
    const float* __restrict__ bta, unsigned short* __restrict__ out)
{
    int wv = threadIdx.x >> 6, lane = threadIdx.x & 63;
    int t = blockIdx.x * 4 + wv;
    const float4 v = *(const float4*)(xr + (size_t)t * C_ + lane * 4);
    float s = v.x + v.y + v.z + v.w;
    float q = v.x * v.x + v.y * v.y + v.z * v.z + v.w * v.w;
    #pragma unroll
    for (int o = 32; o > 0; o >>= 1) {
        s += __shfl_xor(s, o);
        q += __shfl_xor(q, o);
    }
    float m = s * (1.f / C_);
    float r = rsqrtf(q * (1.f / C_) - m * m + 1e-5f);
    float4 gg = *(const float4*)(g + lane * 4);
    float4 bb = *(const float4*)(bta + lane * 4);
    unsigned short o0 = f2bf((v.x - m) * r * gg.x + bb.x);
    unsigned short o1 = f2bf((v.y - m) * r * gg.y + bb.y);
    unsigned short o2 = f2bf((v.z - m) * r * gg.z + bb.z);
    unsigned short o3 = f2bf((v.w - m) * r * gg.w + bb.w);
    unsigned lo = ((unsigned)o1 << 16) | o0;
    unsigned hi = ((unsigned)o3 << 16) | o2;
    *(uint2*)(out + (size_t)t * C_ + lane * 4) = make_uint2(lo, hi);
}

// ============================ MFMA GEMM (global_load_lds staging) ============================
// C[M,N] = A[M,K] @ W[N,K]^T (+ epilogue). bf16 in, fp32 acc.
// 128x128 tile, BK=32, 4 waves (2x2), each wave 4x4 frags of 16x16x32.
// LDS subtile s (16 rows): lane l holds (row = l&15, k = (l>>4)*8+j) at
// shorts [s][l*8+j] == base + l*16B -> matches global_load_lds lane rule.
enum { AB_ROW = 0, AB_CAT = 1, AB_GATHER = 2 };
enum { EB_BF16 = 0, EB_F32 = 1, EG_BF16 = 2, ER_F32 = 3 };

template<int AMODE, int EMODE>
__global__ __launch_bounds__(256) void mgemm(
    const unsigned short* __restrict__ A0, const unsigned short* __restrict__ A1,
    const unsigned short* __restrict__ Wb, const float* __restrict__ bias,
    const float* __restrict__ resid, float* __restrict__ outf,
    unsigned short* __restrict__ outb,
    int K, int lda, int ldw, int ldo, int rowoff)
{
    __shared__ __align__(16) short As[8][512];
    __shared__ __align__(16) short Bs[8][512];
    const int tid = threadIdx.x;
    const int t0 = blockIdx.x * 128;
    const int n0 = blockIdx.y * 128;
    const int lane = tid & 63, wv = tid >> 6;
    const int wr = wv >> 1, wc = wv & 1;
    const int fr = lane & 15;          // row/col within subtile
    const int fk = (lane >> 4) * 8;    // k offset within BK

    // hoisted per-lane source pointers (k-independent part)
    const unsigned short* aptr0 = nullptr;
    const unsigned short* aptr1 = nullptr;
    if (AMODE == AB_GATHER) {
        #pragma unroll
        for (int si = 0; si < 2; ++si) {
            const int gr = rowoff + t0 + (wv * 2 + si) * 16 + fr;
            const int b = gr / HW_;
            const int rem = gr - b * HW_;
            const int w = rem / H_;
            const int h = rem - w * H_;
            const unsigned short* p =
                A0 + ((size_t)b * HW_ + (size_t)h * W_ + w) * 256 + 128 + fk;
            if (si == 0) aptr0 = p; else aptr1 = p;
        }
    } else if (AMODE == AB_ROW) {
        aptr0 = A0 + (size_t)(t0 + (wv * 2 + 0) * 16 + fr) * lda + fk;
        aptr1 = A0 + (size_t)(t0 + (wv * 2 + 1) * 16 + fr) * lda + fk;
    }
    const unsigned short* bptr0 = Wb + (size_t)(n0 + (wv * 2 + 0) * 16 + fr) * ldw + fk;
    const unsigned short* bptr1 = Wb + (size_t)(n0 + (wv * 2 + 1) * 16 + fr) * ldw + fk;

    f32x4 acc[4][4];
    #pragma unroll
    for (int m = 0; m < 4; ++m)
        #pragma unroll
        for (int n = 0; n < 4; ++n)
            acc[m][n] = (f32x4){0.f, 0.f, 0.f, 0.f};

    for (int k0 = 0; k0 < K; k0 += 32) {
        if (AMODE == AB_CAT) {
            const unsigned short* base = (k0 < 128) ? A0 : A1;
            const int kk = (k0 & 127) + fk;
            gload_lds16(base + (size_t)(t0 + (wv * 2 + 0) * 16 + fr) * 128 + kk,
                        &As[wv * 2 + 0][0]);
            gload_lds16(base + (size_t)(t0 + (wv * 2 + 1) * 16 + fr) * 128 + kk,
                        &As[wv * 2 + 1][0]);
        } else {
            gload_lds16(aptr0 + k0, &As[wv * 2 + 0][0]);
            gload_lds16(aptr1 + k0, &As[wv * 2 + 1][0]);
        }
        gload_lds16(bptr0 + k0, &Bs[wv * 2 + 0][0]);
        gload_lds16(bptr1 + k0, &Bs[wv * 2 + 1][0]);
        __syncthreads();
        bf16x8 af[4], bfr[4];
        #pragma unroll
        for (int m = 0; m < 4; ++m)
            af[m] = __builtin_bit_cast(bf16x8, *(const s16x8*)&As[wr * 4 + m][lane * 8]);
        #pragma unroll
        for (int n = 0; n < 4; ++n)
            bfr[n] = __builtin_bit_cast(bf16x8, *(const s16x8*)&Bs[wc * 4 + n][lane * 8]);
        #pragma unroll
        for (int m = 0; m < 4; ++m)
            #pragma unroll
            for (int n = 0; n < 4; ++n)
                acc[m][n] = __builtin_amdgcn_mfma_f32_16x16x32_bf16(
                    af[m], bfr[n], acc[m][n], 0, 0, 0);
        __syncthreads();
    }

    const int rowb = t0 + wr * 64 + (lane >> 4) * 4;
    const int colb = n0 + wc * 64 + (lane & 15);
    #pragma unroll
    for (int n = 0; n < 4; ++n) {
        const int col = colb + n * 16;
        const float bcol = bias[col];
        #pragma unroll
        for (int m = 0; m < 4; ++m) {
            #pragma unroll
            for (int r = 0; r < 4; ++r) {
                const int row = rowb + m * 16 + r;
                float v = acc[m][n][r] + bcol;
                if (EMODE == EG_BF16)
                    v = 0.5f * v * (1.f + erff(v * 0.70710678118654752f));
                if (EMODE == ER_F32)
                    v += resid[(size_t)row * 256 + col];
                if (EMODE == EB_F32 || EMODE == ER_F32)
                    outf[(size_t)row * ldo + col] = v;
                else
                    outb[(size_t)row * ldo + col] = f2bf(v);
            }
        }
    }
}

// x1[t*256+c] += x[(b*C+c)*HW + hw]
__global__ __launch_bounds__(256) void tadd_kernel(
    const float* __restrict__ x, float* __restrict__ x1)
{
    __shared__ float tile[32][33];
    int t0 = blockIdx.x * 32;
    int c0 = blockIdx.y * 32;
    int b = t0 / HW_, hw0 = t0 - b * HW_;
    int tid = threadIdx.x;
    int lane = tid & 31, grp = tid >> 5;
    #pragma unroll
    for (int j = 0; j < 4; ++j) {
        int c = grp + j * 8;
        tile[c][lane] = x[((size_t)b * C_ + c0 + c) * HW_ + hw0 + lane];
    }
    __syncthreads();
    #pragma unroll
    for (int j = 0; j < 4; ++j) {
        int tt = grp + j * 8;
        x1[(size_t)(t0 + tt) * C_ + c0 + lane] += tile[lane][tt];
    }
}

// ============================ MFMA flash attention ============================
template<int N, int DIR>
__global__ __launch_bounds__(256) void attn_mfma_kernel(
    const unsigned short* __restrict__ qkv, unsigned short* __restrict__ outb, int strip0)
{
    constexpr int NT = N / 16;
    constexpr int CH = N / 32;
    constexpr int QTW = N / 64;
    constexpr int PST = N + 8;
    __shared__ __align__(16) short kls[NT * 256];
    __shared__ __align__(16) short vls[CH * 512];
    __shared__ __align__(16) short plds[4 * 16 * PST];
    const int head = blockIdx.x & 7;
    const int sl = blockIdx.x >> 3;
    const int s = strip0 + sl;
    const int tid = threadIdx.x;
    const unsigned short* base = qkv + (size_t)sl * N * 384;
    for (int i = tid; i < 2 * N; i += 256) {
        int r = i >> 1, hf = i & 1;
        s16x8 kv = *(const s16x8*)(base + (size_t)r * 384 + 128 + head * 16 + hf * 8);
        *(s16x8*)&kls[(r >> 4) * 256 + (hf * 16 + (r & 15)) * 8] = kv;
    }
    for (int i = tid; i < 2 * N; i += 256) {
        int r = i >> 1, hf = i & 1;
        s16x8 vv = *(const s16x8*)(base + (size_t)r * 384 + 256 + head * 16 + hf * 8);
        short* dst = &vls[(r >> 5) * 512 + ((r & 31) >> 3) * 128 + (r & 7)];
        #pragma unroll
        for (int j = 0; j < 8; ++j)
            dst[(hf * 8 + j) * 8] = vv[j];
    }
    __syncthreads();
    const int wv = tid >> 6, lane = tid & 63, g = lane >> 4, q = lane & 15;
    short* myP = &plds[wv * 16 * PST];
    const bf16x8 zf = __builtin_bit_cast(bf16x8, (s16x8){0,0,0,0,0,0,0,0});
    for (int qt_i = 0; qt_i < QTW; ++qt_i) {
        const int q0 = wv * (N / 4) + qt_i * 16;
        bf16x8 qf = zf;
        if (lane < 32)
            qf = __builtin_bit_cast(bf16x8,
                *(const s16x8*)(base + (size_t)(q0 + q) * 384 + head * 16 + g * 8));
        f32x4 sc[NT];
        #pragma unroll
        for (int n = 0; n < NT; ++n) {
            bf16x8 kf = zf;
            if (lane < 32)
                kf = __builtin_bit_cast(bf16x8, *(const s16x8*)&kls[n * 256 + lane * 8]);
            sc[n] = __builtin_amdgcn_mfma_f32_16x16x32_bf16(
                kf, qf, (f32x4){0.f, 0.f, 0.f, 0.f}, 0, 0, 0);
        }
        float mx = -3.0e38f;
        #pragma unroll
        for (int n = 0; n < NT; ++n)
            mx = fmaxf(mx, fmaxf(fmaxf(sc[n][0], sc[n][1]), fmaxf(sc[n][2], sc[n][3])));
        mx = fmaxf(mx, __shfl_xor(mx, 16));
        mx = fmaxf(mx, __shfl_xor(mx, 32));
        float sum = 0.f;
        #pragma unroll
        for (int n = 0; n < NT; ++n) {
            float p0 = __expf((sc[n][0] - mx) * 0.25f);
            float p1 = __expf((sc[n][1] - mx) * 0.25f);
            float p2 = __expf((sc[n][2] - mx) * 0.25f);
            float p3 = __expf((sc[n][3] - mx) * 0.25f);
            sum += (p0 + p1) + (p2 + p3);
            unsigned u01 = ((unsigned)bfbits(p1) << 16) | bfbits(p0);
            unsigned u23 = ((unsigned)bfbits(p3) << 16) | bfbits(p2);
            *(unsigned*)&myP[q * PST + n * 16 + g * 4] = u01;
            *(unsigned*)&myP[q * PST + n * 16 + g * 4 + 2] = u23;
        }
        sum += __shfl_xor(sum, 16);
        sum += __shfl_xor(sum, 32);
        const float inv = 1.f / sum;
        f32x4 o = (f32x4){0.f, 0.f, 0.f, 0.f};
        #pragma unroll
        for (int c = 0; c < CH; ++c) {
            bf16x8 vf = __builtin_bit_cast(bf16x8, *(const s16x8*)&vls[c * 512 + lane * 8]);
            bf16x8 pf = __builtin_bit_cast(bf16x8, *(const s16x8*)&myP[q * PST + c * 32 + g * 8]);
            o = __builtin_amdgcn_mfma_f32_16x16x32_bf16(vf, pf, o, 0, 0, 0);
        }
        unsigned lo = ((unsigned)bfbits(o[1] * inv) << 16) | bfbits(o[0] * inv);
        unsigned hi = ((unsigned)bfbits(o[3] * inv) << 16) | bfbits(o[2] * inv);
        size_t dst;
        if (DIR == 0) {
            dst = ((size_t)s * W_ + q0 + q) * 128 + head * 16 + g * 4;
        } else {
            int b = s >> 8, w = s & 255;
            dst = ((size_t)b * HW_ + (size_t)(q0 + q) * W_ + w) * 128 + head * 16 + g * 4;
        }
        *(uint2*)&outb[dst] = make_uint2(lo, hi);
    }
}

// ============================ PEG (depthwise 3x3 + residual) ============================
// tile[32 tokens][132 ch-pad]: float4 writes along channels (conflict-free),
// 2-way (free) scalar reads for the planar transpose store.
__global__ __launch_bounds__(256) void peg_kernel(
    const float* __restrict__ x2t, const float* __restrict__ pw,
    const float* __restrict__ pb, float* __restrict__ outp)
{
    __shared__ float pwt[9][132];
    __shared__ float tile[32][132];
    const int t0 = blockIdx.x * 32;
    const int cbase = blockIdx.y * 128;
    const int b = t0 / HW_, hw0 = t0 - b * HW_;
    const int h = hw0 >> 8, w0 = hw0 & 255;
    const int tid = threadIdx.x;
    for (int i = tid; i < 1152; i += 256) {
        int tap = i >> 7, ch = i & 127;
        pwt[tap][ch] = pw[(size_t)(cbase + ch) * 9 + tap];
    }
    __syncthreads();
    const int c4 = tid & 31;
    const int tg = tid >> 5;
    const int cq = cbase + c4 * 4;
    float4 pb4 = *(const float4*)(pb + cq);
    #pragma unroll
    for (int j = 0; j < 4; ++j) {
        int tt = tg * 4 + j;
        int t = t0 + tt;
        int w = w0 + tt;
        float4 a = *(const float4*)(x2t + (size_t)t * C_ + cq);
        a.x += pb4.x; a.y += pb4.y; a.z += pb4.z; a.w += pb4.w;
        #pragma unroll
        for (int dh = -1; dh <= 1; ++dh) {
            int hh = h + dh;
            if (hh < 0 || hh >= H_) continue;
            #pragma unroll
            for (int dw = -1; dw <= 1; ++dw) {
                int ww = w + dw;
                if (ww < 0 || ww >= W_) continue;
                float4 xv = *(const float4*)(x2t + (size_t)(t + dh * W_ + dw) * C_ + cq);
                float4 wvv = *(const float4*)&pwt[(dh + 1) * 3 + (dw + 1)][c4 * 4];
                a.x += wvv.x * xv.x; a.y += wvv.y * xv.y;
                a.z += wvv.z * xv.z; a.w += wvv.w * xv.w;
            }
        }
        *(float4*)&tile[tt][c4 * 4] = a;
    }
    __syncthreads();
    const int ch = tid >> 1, hf = (tid & 1) * 16;
    float* drow = outp + ((size_t)b * C_ + cbase + ch) * HW_ + hw0 + hf;
    #pragma unroll
    for (int qq = 0; qq < 4; ++qq) {
        float4 vv = make_float4(tile[hf + qq * 4 + 0][ch], tile[hf + qq * 4 + 1][ch],
                                tile[hf + qq * 4 + 2][ch], tile[hf + qq * 4 + 3][ch]);
        *(float4*)(drow + qq * 4) = vv;
    }
}

// ============================ launcher ============================
extern "C" void kernel_launch(void* const* d_in, const int* in_sizes, int n_in,
                              void* d_out, int out_size, void* d_ws, size_t ws_size,
                              hipStream_t stream)
{
    (void)in_sizes; (void)n_in; (void)out_size; (void)ws_size;
    const float* x         = (const float*)d_in[0];
    const float* ln1_g     = (const float*)d_in[1];
    const float* ln1_b     = (const float*)d_in[2];
    const float* conv_in_w = (const float*)d_in[3];
    const float* conv_in_b = (const float*)d_in[4];
    const float* qkv_h_w   = (const float*)d_in[5];
    const float* qkv_h_b   = (const float*)d_in[6];
    const float* qkv_v_w   = (const float*)d_in[7];
    const float* qkv_v_b   = (const float*)d_in[8];
    const float* fuse_w    = (const float*)d_in[9];
    const float* fuse_b    = (const float*)d_in[10];
    const float* ln2_g     = (const float*)d_in[11];
    const float* ln2_b     = (const float*)d_in[12];
    const float* fc1_w     = (const float*)d_in[13];
    const float* fc1_b     = (const float*)d_in[14];
    const float* fc2_w     = (const float*)d_in[15];
    const float* fc2_b     = (const float*)d_in[16];
    const float* peg_w     = (const float*)d_in[17];
    const float* peg_b     = (const float*)d_in[18];
    float* outp = (float*)d_out;

    // workspace (~204 MB)
    float* wsf   = (float*)d_ws;
    float* mean1 = wsf;
    float* rstd1 = wsf + (size_t)T_;
    float* x1    = wsf + 2 * (size_t)T_;                           // [T,256] f32
    unsigned short* xn = (unsigned short*)x1;                      // [T,256] bf16
    unsigned short* ci = (unsigned short*)(x1 + (size_t)T_ * 128); // [T,256] bf16
    unsigned short* ah = (unsigned short*)(x1 + (size_t)T_ * 256); // [T,128] bf16
    unsigned short* av = ah + (size_t)T_ * 128;                    // [T,128] bf16
    unsigned short* xn2 = ah;                                      // [T,256] bf16 (post-fuse)
    unsigned short* qt = av + (size_t)T_ * 128;                    // chunk buf: 24576x1024 bf16
    unsigned short* wb = qt + (size_t)24576 * 1024;
    unsigned short* wconv = wb;
    unsigned short* wqh   = wconv + 65536;
    unsigned short* wqv   = wqh + 49152;
    unsigned short* wfu   = wqv + 49152;
    unsigned short* wf1   = wfu + 65536;
    unsigned short* wf2   = wf1 + 262144;

    dim3 blk(256);

    wcvt_kernel<<<dim3(64), blk, 0, stream>>>(conv_in_w, wconv, 65536);
    wcvt_kernel<<<dim3(48), blk, 0, stream>>>(qkv_h_w, wqh, 49152);
    wcvt_kernel<<<dim3(48), blk, 0, stream>>>(qkv_v_w, wqv, 49152);
    wcvt_kernel<<<dim3(64), blk, 0, stream>>>(fuse_w, wfu, 65536);
    wcvt_kernel<<<dim3(256), blk, 0, stream>>>(fc1_w, wf1, 262144);
    wcvt_kernel<<<dim3(256), blk, 0, stream>>>(fc2_w, wf2, 262144);
    // 1. LN1 stats + normalized bf16 row-major
    ln1_stats_kernel<<<dim3(T_ / 256), blk, 0, stream>>>(x, mean1, rstd1);
    xln_kernel<<<dim3(T_ / 32, 8), blk, 0, stream>>>(x, mean1, rstd1, ln1_g, ln1_b, xn);
    // 2. conv_in
    mgemm<AB_ROW, EB_BF16><<<dim3(768, 2), blk, 0, stream>>>(
        xn, nullptr, wconv, conv_in_b, nullptr, nullptr, ci, 256, 256, 256, 256, 0);
    // 3. horizontal attention: 2 chunks of 192 strips (49152 tokens)
    for (int ch = 0; ch < 2; ++ch) {
        const size_t r0 = (size_t)ch * 49152;
        mgemm<AB_ROW, EB_BF16><<<dim3(384, 3), blk, 0, stream>>>(
            ci + r0 * 256, nullptr, wqh, qkv_h_b, nullptr, nullptr, qt,
            128, 256, 128, 384, 0);
        attn_mfma_kernel<256, 0><<<dim3(192 * 8), blk, 0, stream>>>(qt, ah, ch * 192);
    }
    // 4. vertical attention: 2 chunks of 256 strips (49152 rows, (b,w,h) order)
    for (int cv = 0; cv < 2; ++cv) {
        mgemm<AB_GATHER, EB_BF16><<<dim3(384, 3), blk, 0, stream>>>(
            ci, nullptr, wqv, qkv_v_b, nullptr, nullptr, qt,
            128, 0, 128, 384, cv * 49152);
        attn_mfma_kernel<192, 1><<<dim3(256 * 8), blk, 0, stream>>>(qt, av, cv * 256);
    }
    // 5. fuse -> x1 (fp32, overwrites xn/ci)
    mgemm<AB_CAT, EB_F32><<<dim3(768, 2), blk, 0, stream>>>(
        ah, av, wfu, fuse_b, nullptr, x1, nullptr, 256, 128, 256, 256, 0);
    // 6. x1 += x (planar residual)
    tadd_kernel<<<dim3(T_ / 32, 8), blk, 0, stream>>>(x, x1);
    // 7. LN2 fused stats+normalize -> xn2 (bf16, overwrites ah/av)
    ln2norm_kernel<<<dim3(T_ / 4), blk, 0, stream>>>(x1, ln2_g, ln2_b, xn2);
    // 8. FFN: 4 token chunks of 24576 rows, in-place residual into x1
    for (int cs = 0; cs < 4; ++cs) {
        const size_t r0 = (size_t)cs * 24576;
        mgemm<AB_ROW, EG_BF16><<<dim3(192, 8), blk, 0, stream>>>(
            xn2 + r0 * 256, nullptr, wf1, fc1_b, nullptr, nullptr, qt,
            256, 256, 256, 1024, 0);
        mgemm<AB_ROW, ER_F32><<<dim3(192, 2), blk, 0, stream>>>(
            qt, nullptr, wf2, fc2_b, x1 + r0 * 256, x1 + r0 * 256, nullptr,
            1024, 1024, 1024, 256, 0);
    }
    // 9. PEG + residual -> planar output
    peg_kernel<<<dim3(T_ / 32, 2), blk, 0, stream>>>(x1, peg_w, peg_b, outp);
}